// Round 1
// baseline (1803.409 us; speedup 1.0000x reference)
//
#include <hip/hip_runtime.h>
#include <math.h>

#define DIMC 96
#define DINC 192
#define NSTC 16
#define DTRC 6
#define KDIR 4
#define BB   2
#define HH   56
#define WWD  56
#define LL   3136            // HH*WWD
#define NPIX (BB*LL)         // 6272
#define EPSF 1e-5f

// ---------- workspace layout (float offsets) ----------
#define OFF_XN     0u          // 602112   xn (B,L,96)
#define OFF_XCRAW  602112u     // 1204224  xc pre-conv NCHW (B,192,L); reused as y_t after scan
#define OFF_ZS     1806336u    // 1204224  silu(z) (B,L,192)
#define OFF_XCONV  3010560u    // 1204224  silu(conv(xc)) NCHW; reused as yact after combine
#define OFF_DTS    4214784u    // 150528   dts (B,K,L,6)
#define OFF_BC     4365312u    // 802816   interleaved (B,K,L,16,{B,C})
#define OFF_DPACK  5168128u    // 9633792  (B,K,192,L) float2 {delta, delta*x}
#define OFF_YS     14801920u   // 4816896  ys (B,K,192,L) in scan order l
// reuse after scan:
#define OFF_YT     OFF_XCRAW
#define OFF_YACT   OFF_XCONV
#define OFF_VL     OFF_DPACK               // 602112
#define OFF_H1     (OFF_DPACK + 1000000u)  // 150528
#define OFF_H2     (OFF_DPACK + 1200000u)  // 150528
#define OFF_H3     OFF_XN                  // 602112
#define OFF_POOL   (OFF_DPACK + 1400000u)  // 192
#define OFF_SEW    (OFF_DPACK + 1400448u)  // 192
#define WS_FLOATS  19618816u               // ~78.5 MB

__device__ __forceinline__ float siluf(float x) { return x / (1.f + __expf(-x)); }
__device__ __forceinline__ float softplusf(float x) {
    return fmaxf(x, 0.f) + log1pf(__expf(-fabsf(x)));
}
__device__ __forceinline__ int pos_of_l(int k, int l) {
    if (k == 0) return l;
    if (k == 1) return (l % HH) * WWD + (l / HH);
    if (k == 2) return LL - 1 - l;
    int lp = LL - 1 - l;
    return (lp % HH) * WWD + (lp / HH);
}

// ---------- 1. LN over C=96 of NCHW input -> xn (B,L,96) ----------
__global__ __launch_bounds__(256) void ln1_k(const float* __restrict__ x,
                                             const float* __restrict__ g,
                                             const float* __restrict__ bt,
                                             float* __restrict__ xn) {
    int pix = blockIdx.x * 4 + (threadIdx.x >> 6);
    int lane = threadIdx.x & 63;
    int b = pix / LL, pos = pix % LL;
    const float* xp = x + (size_t)b * DIMC * LL + pos;
    float a0 = xp[(size_t)lane * LL];
    float a1 = (lane < 32) ? xp[(size_t)(lane + 64) * LL] : 0.f;
    float s = a0 + a1, q = a0 * a0 + a1 * a1;
    for (int o = 32; o; o >>= 1) { s += __shfl_xor(s, o, 64); q += __shfl_xor(q, o, 64); }
    float m = s * (1.f / 96.f);
    float inv = rsqrtf(q * (1.f / 96.f) - m * m + EPSF);
    float* op = xn + (size_t)pix * DIMC;
    op[lane] = (a0 - m) * inv * g[lane] + bt[lane];
    if (lane < 32) op[lane + 64] = (a1 - m) * inv * g[lane + 64] + bt[lane + 64];
}

// ---------- 2. in_proj GEMM: (6272,96)@(96,384)^T -> xc_raw NCHW + silu(z) HWC ----------
__global__ __launch_bounds__(384) void gemm1_k(const float* __restrict__ xn,
                                               const float* __restrict__ W,
                                               float* __restrict__ xcr,
                                               float* __restrict__ zs) {
    __shared__ float xs[8][96];
    int row0 = blockIdx.x * 8;
    for (int i = threadIdx.x; i < 768; i += 384) xs[i / 96][i % 96] = xn[(size_t)row0 * 96 + i];
    __syncthreads();
    int col = threadIdx.x;  // 0..383
    const float* wr = W + (size_t)col * DIMC;
    float acc[8] = {0, 0, 0, 0, 0, 0, 0, 0};
    for (int c0 = 0; c0 < 96; c0 += 4) {
        float4 wv = *(const float4*)(wr + c0);
#pragma unroll
        for (int r = 0; r < 8; ++r) {
            float4 xv = *(const float4*)(&xs[r][c0]);
            acc[r] = fmaf(xv.x, wv.x, acc[r]);
            acc[r] = fmaf(xv.y, wv.y, acc[r]);
            acc[r] = fmaf(xv.z, wv.z, acc[r]);
            acc[r] = fmaf(xv.w, wv.w, acc[r]);
        }
    }
#pragma unroll
    for (int r = 0; r < 8; ++r) {
        int row = row0 + r, b = row / LL, pos = row % LL;
        if (col < DINC) xcr[((size_t)b * DINC + col) * LL + pos] = acc[r];
        else            zs[(size_t)row * DINC + (col - DINC)] = siluf(acc[r]);
    }
}

// ---------- 3. depthwise 3x3 conv + bias + silu ----------
__global__ __launch_bounds__(256) void dwconv_k(const float* __restrict__ xcr,
                                                const float* __restrict__ cw,
                                                const float* __restrict__ cb,
                                                float* __restrict__ xconv) {
    int i = blockIdx.x * 256 + threadIdx.x;  // < B*DIN*LL
    int pos = i % LL, d = (i / LL) % DINC, b = i / (LL * DINC);
    int hh = pos / WWD, ww = pos % WWD;
    const float* src = xcr + ((size_t)b * DINC + d) * LL;
    const float* wk = cw + d * 9;
    float acc = cb[d];
#pragma unroll
    for (int ky = 0; ky < 3; ++ky) {
        int y = hh + ky - 1;
        if ((unsigned)y >= HH) continue;
#pragma unroll
        for (int kx = 0; kx < 3; ++kx) {
            int xq = ww + kx - 1;
            if ((unsigned)xq >= WWD) continue;
            acc = fmaf(wk[ky * 3 + kx], src[y * WWD + xq], acc);
        }
    }
    xconv[i] = siluf(acc);
}

// ---------- 4. x_proj: per (b,k,l) 38 dots over d=192 -> dts + interleaved B/C ----------
__global__ __launch_bounds__(256) void xdbl_k(const float* __restrict__ xconv,
                                              const float* __restrict__ xpw,
                                              float* __restrict__ dts,
                                              float* __restrict__ bc) {
    int g = blockIdx.x * 4 + (threadIdx.x >> 6);  // (b,k,l) group, one wave each
    int lane = threadIdx.x & 63;
    int l = g % LL, k = (g / LL) % KDIR, b = g / (LL * KDIR);
    int pos = pos_of_l(k, l);
    const float* xc = xconv + (size_t)b * DINC * LL + pos;
    bool act = lane < 38;
    const float* wp = xpw + ((size_t)k * 38 + (act ? lane : 0)) * DINC;
    float acc = 0.f;
#pragma unroll 8
    for (int dd = 0; dd < DINC; ++dd) {
        float xv = xc[(size_t)dd * LL];  // broadcast
        acc = fmaf(wp[dd], xv, acc);
    }
    size_t rb = (size_t)(b * KDIR + k) * LL + l;
    if (lane < DTRC)      dts[rb * DTRC + lane] = acc;
    else if (lane < 22)   bc[(rb * NSTC + (lane - 6)) * 2 + 0] = acc;
    else if (lane < 38)   bc[(rb * NSTC + (lane - 22)) * 2 + 1] = acc;
}

// ---------- 5. delta pack: {softplus(dt), softplus(dt)*x} per (b,k,d,l) ----------
__global__ __launch_bounds__(256) void dpack_k(const float* __restrict__ dts,
                                               const float* __restrict__ xconv,
                                               const float* __restrict__ dtw,
                                               const float* __restrict__ dtb,
                                               float2* __restrict__ dpk) {
    int i = blockIdx.x * 256 + threadIdx.x;  // < B*K*DIN*LL
    int l = i % LL, d = (i / LL) % DINC, k = (i / (LL * DINC)) % KDIR, b = i / (LL * DINC * KDIR);
    int pos = pos_of_l(k, l);
    const float* dr = dts + ((size_t)(b * KDIR + k) * LL + l) * DTRC;
    const float* wr = dtw + ((size_t)k * DINC + d) * DTRC;
    float acc = dtb[k * DINC + d];
#pragma unroll
    for (int r = 0; r < DTRC; ++r) acc = fmaf(wr[r], dr[r], acc);
    float dv = softplusf(acc);
    float xv = xconv[((size_t)b * DINC + d) * LL + pos];
    dpk[i] = make_float2(dv, dv * xv);
}

// ---------- 6. selective scan: 16 lanes per chain (lane = state n) ----------
__global__ __launch_bounds__(64) void scan_k(const float2* __restrict__ dpk,
                                             const float2* __restrict__ bc,
                                             const float* __restrict__ alog,
                                             float* __restrict__ ys) {
    int chain = blockIdx.x * 4 + (threadIdx.x >> 4);  // 0..1535 == (b*4+k)*192+d
    int lane = threadIdx.x & 15;
    float An = -__expf(alog[(size_t)(chain % (KDIR * DINC) == chain % (KDIR * DINC) ? 0 : 0) +
                            (size_t)((chain % (KDIR * DINC))) * NSTC + lane]);
    // chain%768 == k*192+d, which indexes A_log rows directly
    const float2* dpr = dpk + (size_t)chain * LL;
    const float2* bcr = bc + (size_t)(chain / DINC) * LL * NSTC + lane;
    float* yr = ys + (size_t)chain * LL;
    float h = 0.f;
#pragma unroll 4
    for (int l = 0; l < LL; ++l) {
        float2 dpv = dpr[l];
        float2 bcv = bcr[(size_t)l * NSTC];
        float dA = __expf(dpv.x * An);
        h = fmaf(dA, h, dpv.y * bcv.x);
        float p = h * bcv.y;
        p += __shfl_xor(p, 1, 16);
        p += __shfl_xor(p, 2, 16);
        p += __shfl_xor(p, 4, 16);
        p += __shfl_xor(p, 8, 16);
        if (lane == 0) yr[l] = p;
    }
}

// ---------- 7. combine 4 directions (+ D*x term) -> y_t NCHW ----------
__global__ __launch_bounds__(256) void combine_k(const float* __restrict__ ys,
                                                 const float* __restrict__ xconv,
                                                 const float* __restrict__ dsv,
                                                 float* __restrict__ yt) {
    int i = blockIdx.x * 256 + threadIdx.x;  // < B*DIN*LL
    int pos = i % LL, d = (i / LL) % DINC, b = i / (LL * DINC);
    int h = pos / WWD, w = pos % WWD;
    int l1 = w * HH + h;
    size_t c0 = ((size_t)(b * KDIR + 0) * DINC + d) * LL;
    size_t c1 = ((size_t)(b * KDIR + 1) * DINC + d) * LL;
    size_t c2 = ((size_t)(b * KDIR + 2) * DINC + d) * LL;
    size_t c3 = ((size_t)(b * KDIR + 3) * DINC + d) * LL;
    float y = ys[c0 + pos] + ys[c1 + l1] + ys[c2 + (LL - 1 - pos)] + ys[c3 + (LL - 1 - l1)];
    float sumD = dsv[d] + dsv[DINC + d] + dsv[2 * DINC + d] + dsv[3 * DINC + d];
    y = fmaf(xconv[((size_t)b * DINC + d) * LL + pos], sumD, y);
    yt[i] = y;
}

// ---------- 8. out_norm LN over 192 * silu(z) -> yact (B,L,192) ----------
__global__ __launch_bounds__(256) void lnmul_k(const float* __restrict__ yt,
                                               const float* __restrict__ g,
                                               const float* __restrict__ bt,
                                               const float* __restrict__ zs,
                                               float* __restrict__ yact) {
    int pix = blockIdx.x * 4 + (threadIdx.x >> 6);
    int lane = threadIdx.x & 63;
    int b = pix / LL, pos = pix % LL;
    const float* yp = yt + (size_t)b * DINC * LL + pos;
    float v0 = yp[(size_t)lane * LL];
    float v1 = yp[(size_t)(lane + 64) * LL];
    float v2 = yp[(size_t)(lane + 128) * LL];
    float s = v0 + v1 + v2, q = v0 * v0 + v1 * v1 + v2 * v2;
    for (int o = 32; o; o >>= 1) { s += __shfl_xor(s, o, 64); q += __shfl_xor(q, o, 64); }
    float m = s * (1.f / 192.f);
    float inv = rsqrtf(q * (1.f / 192.f) - m * m + EPSF);
    float* op = yact + (size_t)pix * DINC;
    const float* zp = zs + (size_t)pix * DINC;
    op[lane] = ((v0 - m) * inv * g[lane] + bt[lane]) * zp[lane];
    op[lane + 64] = ((v1 - m) * inv * g[lane + 64] + bt[lane + 64]) * zp[lane + 64];
    op[lane + 128] = ((v2 - m) * inv * g[lane + 128] + bt[lane + 128]) * zp[lane + 128];
}

// ---------- 9. out_proj GEMM + scaled residual -> vl (B,L,96) ----------
__global__ __launch_bounds__(384) void gemm2_k(const float* __restrict__ yact,
                                               const float* __restrict__ opw,
                                               const float* __restrict__ x,
                                               const float* __restrict__ sc1,
                                               float* __restrict__ vl) {
    __shared__ float ysl[16][192];
    int row0 = blockIdx.x * 16;
    for (int i = threadIdx.x; i < 16 * 192; i += 384)
        ysl[i / 192][i % 192] = yact[(size_t)row0 * DINC + i];
    __syncthreads();
    int col = threadIdx.x % 96;
    int rs = threadIdx.x / 96;  // 0..3
    const float* wr = opw + (size_t)col * DINC;
    float acc[4] = {0, 0, 0, 0};
    for (int c0 = 0; c0 < DINC; c0 += 4) {
        float4 wv = *(const float4*)(wr + c0);
#pragma unroll
        for (int i = 0; i < 4; ++i) {
            float4 xv = *(const float4*)(&ysl[rs + 4 * i][c0]);
            acc[i] = fmaf(xv.x, wv.x, acc[i]);
            acc[i] = fmaf(xv.y, wv.y, acc[i]);
            acc[i] = fmaf(xv.z, wv.z, acc[i]);
            acc[i] = fmaf(xv.w, wv.w, acc[i]);
        }
    }
#pragma unroll
    for (int i = 0; i < 4; ++i) {
        int row = row0 + rs + 4 * i, b = row / LL, pos = row % LL;
        float v = fmaf(sc1[col], x[((size_t)b * DIMC + col) * LL + pos], acc[i]);
        vl[(size_t)row * DIMC + col] = v;
    }
}

// ---------- 10. LN2 + conv1x1(96->24) + BN + ReLU -> h1 NCHW ----------
__global__ __launch_bounds__(256) void ln2conv1_k(const float* __restrict__ vl,
                                                  const float* __restrict__ g,
                                                  const float* __restrict__ bt,
                                                  const float* __restrict__ w1,
                                                  const float* __restrict__ g1,
                                                  const float* __restrict__ b1,
                                                  const float* __restrict__ m1,
                                                  const float* __restrict__ v1,
                                                  float* __restrict__ h1) {
    __shared__ float row[4][96];
    int wv = threadIdx.x >> 6, lane = threadIdx.x & 63;
    int pix = blockIdx.x * 4 + wv;
    const float* vr = vl + (size_t)pix * DIMC;
    float a0 = vr[lane];
    float a1 = (lane < 32) ? vr[64 + lane] : 0.f;
    float s = a0 + a1, q = a0 * a0 + a1 * a1;
    for (int o = 32; o; o >>= 1) { s += __shfl_xor(s, o, 64); q += __shfl_xor(q, o, 64); }
    float m = s * (1.f / 96.f);
    float inv = rsqrtf(q * (1.f / 96.f) - m * m + EPSF);
    row[wv][lane] = (a0 - m) * inv * g[lane] + bt[lane];
    if (lane < 32) row[wv][64 + lane] = (a1 - m) * inv * g[64 + lane] + bt[64 + lane];
    __syncthreads();
    if (lane < 24) {
        const float* wr = w1 + lane * 96;
        float acc = 0.f;
#pragma unroll 8
        for (int c = 0; c < 96; ++c) acc = fmaf(row[wv][c], wr[c], acc);
        float bn = (acc - m1[lane]) * rsqrtf(v1[lane] + EPSF) * g1[lane] + b1[lane];
        int b = pix / LL, pos = pix % LL;
        h1[((size_t)b * 24 + lane) * LL + pos] = fmaxf(bn, 0.f);
    }
}

// ---------- 11. conv3x3 (24->24) + BN + ReLU ----------
__global__ __launch_bounds__(256) void conv2_k(const float* __restrict__ h1,
                                               const float* __restrict__ w2,
                                               const float* __restrict__ g2,
                                               const float* __restrict__ b2,
                                               const float* __restrict__ m2,
                                               const float* __restrict__ v2,
                                               float* __restrict__ h2) {
    int i = blockIdx.x * 256 + threadIdx.x;  // < B*24*LL
    int pos = i % LL, mo = (i / LL) % 24, b = i / (LL * 24);
    int hh = pos / WWD, ww = pos % WWD;
    float acc = 0.f;
    for (int c = 0; c < 24; ++c) {
        const float* src = h1 + ((size_t)b * 24 + c) * LL;
        const float* wk = w2 + ((size_t)(mo * 24 + c)) * 9;
#pragma unroll
        for (int ky = 0; ky < 3; ++ky) {
            int y = hh + ky - 1;
            if ((unsigned)y >= HH) continue;
#pragma unroll
            for (int kx = 0; kx < 3; ++kx) {
                int xq = ww + kx - 1;
                if ((unsigned)xq >= WWD) continue;
                acc = fmaf(wk[ky * 3 + kx], src[y * WWD + xq], acc);
            }
        }
    }
    float bn = (acc - m2[mo]) * rsqrtf(v2[mo] + EPSF) * g2[mo] + b2[mo];
    h2[i] = fmaxf(bn, 0.f);
}

// ---------- 12. conv1x1 (24->96) + BN -> h3 NCHW ----------
__global__ __launch_bounds__(256) void conv3_k(const float* __restrict__ h2,
                                               const float* __restrict__ w3,
                                               const float* __restrict__ g3,
                                               const float* __restrict__ b3,
                                               const float* __restrict__ m3,
                                               const float* __restrict__ v3,
                                               float* __restrict__ h3) {
    int i = blockIdx.x * 256 + threadIdx.x;  // < B*96*LL
    int pos = i % LL, c = (i / LL) % DIMC, b = i / (LL * DIMC);
    const float* wr = w3 + c * 24;
    float acc = 0.f;
#pragma unroll
    for (int mo = 0; mo < 24; ++mo)
        acc = fmaf(wr[mo], h2[((size_t)b * 24 + mo) * LL + pos], acc);
    h3[i] = (acc - m3[c]) * rsqrtf(v3[c] + EPSF) * g3[c] + b3[c];
}

// ---------- 13. SE pool: mean over L per (b,c) ----------
__global__ __launch_bounds__(256) void pool_k(const float* __restrict__ h3,
                                              float* __restrict__ pooled) {
    int bc = blockIdx.x;  // 0..191
    const float* p = h3 + (size_t)bc * LL;
    float s = 0.f;
    for (int i = threadIdx.x; i < LL; i += 256) s += p[i];
    for (int o = 32; o; o >>= 1) s += __shfl_xor(s, o, 64);
    __shared__ float wsum[4];
    if ((threadIdx.x & 63) == 0) wsum[threadIdx.x >> 6] = s;
    __syncthreads();
    if (threadIdx.x == 0) pooled[bc] = (wsum[0] + wsum[1] + wsum[2] + wsum[3]) * (1.f / 3136.f);
}

// ---------- 14. SE MLP ----------
__global__ __launch_bounds__(128) void semlp_k(const float* __restrict__ pooled,
                                               const float* __restrict__ sw1,
                                               const float* __restrict__ sw2,
                                               float* __restrict__ sew) {
    __shared__ float pl[2][96];
    __shared__ float hid[2][24];
    for (int i = threadIdx.x; i < 192; i += 128) pl[i / 96][i % 96] = pooled[i];
    __syncthreads();
    if (threadIdx.x < 48) {
        int b = threadIdx.x / 24, mo = threadIdx.x % 24;
        float acc = 0.f;
        for (int c = 0; c < 96; ++c) acc = fmaf(pl[b][c], sw1[mo * 96 + c], acc);
        hid[b][mo] = fmaxf(acc, 0.f);
    }
    __syncthreads();
    for (int i = threadIdx.x; i < 192; i += 128) {
        int b = i / 96, c = i % 96;
        float acc = 0.f;
        for (int mo = 0; mo < 24; ++mo) acc = fmaf(hid[b][mo], sw2[c * 24 + mo], acc);
        sew[i] = 1.f / (1.f + __expf(-acc));
    }
}

// ---------- 15. final: h3*se + scale2*vl ----------
__global__ __launch_bounds__(256) void final_k(const float* __restrict__ h3,
                                               const float* __restrict__ sew,
                                               const float* __restrict__ vl,
                                               const float* __restrict__ sc2,
                                               float* __restrict__ out) {
    int i = blockIdx.x * 256 + threadIdx.x;  // < B*96*LL
    int pos = i % LL, c = (i / LL) % DIMC, b = i / (LL * DIMC);
    out[i] = fmaf(h3[i], sew[b * DIMC + c],
                  sc2[c] * vl[((size_t)b * LL + pos) * DIMC + c]);
}

extern "C" void kernel_launch(void* const* d_in, const int* in_sizes, int n_in,
                              void* d_out, int out_size, void* d_ws, size_t ws_size,
                              hipStream_t stream) {
    const float* x    = (const float*)d_in[0];
    const float* n1g  = (const float*)d_in[1];
    const float* n1b  = (const float*)d_in[2];
    const float* ipw  = (const float*)d_in[3];
    const float* cw   = (const float*)d_in[4];
    const float* cb   = (const float*)d_in[5];
    const float* xpw  = (const float*)d_in[6];
    const float* dtw  = (const float*)d_in[7];
    const float* dtb  = (const float*)d_in[8];
    const float* alog = (const float*)d_in[9];
    const float* dsv  = (const float*)d_in[10];
    const float* ong  = (const float*)d_in[11];
    const float* onb  = (const float*)d_in[12];
    const float* opw  = (const float*)d_in[13];
    const float* sc1  = (const float*)d_in[14];
    const float* n2g  = (const float*)d_in[15];
    const float* n2b  = (const float*)d_in[16];
    const float* w1   = (const float*)d_in[17];
    const float* g1   = (const float*)d_in[18];
    const float* b1   = (const float*)d_in[19];
    const float* m1   = (const float*)d_in[20];
    const float* v1   = (const float*)d_in[21];
    const float* w2   = (const float*)d_in[22];
    const float* g2   = (const float*)d_in[23];
    const float* b2   = (const float*)d_in[24];
    const float* m2   = (const float*)d_in[25];
    const float* v2   = (const float*)d_in[26];
    const float* w3   = (const float*)d_in[27];
    const float* g3   = (const float*)d_in[28];
    const float* b3   = (const float*)d_in[29];
    const float* m3   = (const float*)d_in[30];
    const float* v3   = (const float*)d_in[31];
    const float* sw1  = (const float*)d_in[32];
    const float* sw2  = (const float*)d_in[33];
    const float* sc2  = (const float*)d_in[34];
    float* ws = (float*)d_ws;
    float* out = (float*)d_out;

    // 1. LN1
    ln1_k<<<NPIX / 4, 256, 0, stream>>>(x, n1g, n1b, ws + OFF_XN);
    // 2. in_proj
    gemm1_k<<<NPIX / 8, 384, 0, stream>>>(ws + OFF_XN, ipw, ws + OFF_XCRAW, ws + OFF_ZS);
    // 3. depthwise conv + silu
    dwconv_k<<<(BB * DINC * LL) / 256, 256, 0, stream>>>(ws + OFF_XCRAW, cw, cb, ws + OFF_XCONV);
    // 4. x_proj -> dts + B/C
    xdbl_k<<<(BB * KDIR * LL) / 4, 256, 0, stream>>>(ws + OFF_XCONV, xpw, ws + OFF_DTS, ws + OFF_BC);
    // 5. delta pack
    dpack_k<<<(BB * KDIR * DINC * LL) / 256, 256, 0, stream>>>(
        ws + OFF_DTS, ws + OFF_XCONV, dtw, dtb, (float2*)(ws + OFF_DPACK));
    // 6. selective scan
    scan_k<<<(BB * KDIR * DINC) / 4, 64, 0, stream>>>(
        (const float2*)(ws + OFF_DPACK), (const float2*)(ws + OFF_BC), alog, ws + OFF_YS);
    // 7. combine directions
    combine_k<<<(BB * DINC * LL) / 256, 256, 0, stream>>>(ws + OFF_YS, ws + OFF_XCONV, dsv,
                                                          ws + OFF_YT);
    // 8. out_norm * silu(z)
    lnmul_k<<<NPIX / 4, 256, 0, stream>>>(ws + OFF_YT, ong, onb, ws + OFF_ZS, ws + OFF_YACT);
    // 9. out_proj + residual
    gemm2_k<<<NPIX / 16, 384, 0, stream>>>(ws + OFF_YACT, opw, x, sc1, ws + OFF_VL);
    // 10. LN2 + conv1
    ln2conv1_k<<<NPIX / 4, 256, 0, stream>>>(ws + OFF_VL, n2g, n2b, w1, g1, b1, m1, v1,
                                             ws + OFF_H1);
    // 11. conv2
    conv2_k<<<(BB * 24 * LL) / 256, 256, 0, stream>>>(ws + OFF_H1, w2, g2, b2, m2, v2,
                                                      ws + OFF_H2);
    // 12. conv3
    conv3_k<<<(BB * DIMC * LL) / 256, 256, 0, stream>>>(ws + OFF_H2, w3, g3, b3, m3, v3,
                                                        ws + OFF_H3);
    // 13-14. SE
    pool_k<<<BB * DIMC, 256, 0, stream>>>(ws + OFF_H3, ws + OFF_POOL);
    semlp_k<<<1, 128, 0, stream>>>(ws + OFF_POOL, sw1, sw2, ws + OFF_SEW);
    // 15. final
    final_k<<<(BB * DIMC * LL) / 256, 256, 0, stream>>>(ws + OFF_H3, ws + OFF_SEW, ws + OFF_VL,
                                                        sc2, out);
    (void)in_sizes; (void)n_in; (void)out_size; (void)ws_size;
}

// Round 2
// 802.423 us; speedup vs baseline: 2.2475x; 2.2475x over previous
//
#include <hip/hip_runtime.h>
#include <math.h>

#define DIMC 96
#define DINC 192
#define NSTC 16
#define DTRC 6
#define KDIR 4
#define BB   2
#define HH   56
#define WWD  56
#define LL   3136            // HH*WWD
#define NPIX (BB*LL)         // 6272
#define EPSF 1e-5f
#define NCH  49              // chunks per chain
#define LC   64              // chunk length (49*64 = 3136)
#define NCHAIN (BB*KDIR*DINC)  // 1536

// ---------- workspace layout (float offsets) ----------
#define OFF_XN     0u          // 602112   xn (B,L,96); reused as sumd during scan; H3 later
#define OFF_XCRAW  602112u     // 1204224  xc pre-conv NCHW; reused as hend/hpre during scan; y_t after
#define OFF_ZS     1806336u    // 1204224  silu(z) (B,L,192)
#define OFF_XCONV  3010560u    // 1204224  silu(conv(xc)) NCHW; reused as yact after combine
#define OFF_DTS    4214784u    // 150528   dts (B,K,L,6)
#define OFF_BC     4365312u    // 802816   interleaved (B,K,L,16,{B,C})
#define OFF_DPACK  5168128u    // 9633792  (B,K,192,L) float2 {delta, delta*x}
#define OFF_YS     14801920u   // 4816896  ys (B,K,192,L) in scan order l
// scan scratch (reuse):
#define OFF_HEND   OFF_XCRAW   // 1536*49*16 = 1204224 floats exactly
#define OFF_SUMD   OFF_XN      // 1536*49 = 75264 floats
// reuse after scan:
#define OFF_YT     OFF_XCRAW
#define OFF_YACT   OFF_XCONV
#define OFF_VL     OFF_DPACK               // 602112
#define OFF_H1     (OFF_DPACK + 1000000u)  // 150528
#define OFF_H2     (OFF_DPACK + 1200000u)  // 150528
#define OFF_H3     OFF_XN                  // 602112
#define OFF_POOL   (OFF_DPACK + 1400000u)  // 192
#define OFF_SEW    (OFF_DPACK + 1400448u)  // 192

__device__ __forceinline__ float siluf(float x) { return x / (1.f + __expf(-x)); }
__device__ __forceinline__ float softplusf(float x) {
    return fmaxf(x, 0.f) + log1pf(__expf(-fabsf(x)));
}
__device__ __forceinline__ int pos_of_l(int k, int l) {
    if (k == 0) return l;
    if (k == 1) return (l % HH) * WWD + (l / HH);
    if (k == 2) return LL - 1 - l;
    int lp = LL - 1 - l;
    return (lp % HH) * WWD + (lp / HH);
}

// ---------- 1. LN over C=96 of NCHW input -> xn (B,L,96) ----------
__global__ __launch_bounds__(256) void ln1_k(const float* __restrict__ x,
                                             const float* __restrict__ g,
                                             const float* __restrict__ bt,
                                             float* __restrict__ xn) {
    int pix = blockIdx.x * 4 + (threadIdx.x >> 6);
    int lane = threadIdx.x & 63;
    int b = pix / LL, pos = pix % LL;
    const float* xp = x + (size_t)b * DIMC * LL + pos;
    float a0 = xp[(size_t)lane * LL];
    float a1 = (lane < 32) ? xp[(size_t)(lane + 64) * LL] : 0.f;
    float s = a0 + a1, q = a0 * a0 + a1 * a1;
    for (int o = 32; o; o >>= 1) { s += __shfl_xor(s, o, 64); q += __shfl_xor(q, o, 64); }
    float m = s * (1.f / 96.f);
    float inv = rsqrtf(q * (1.f / 96.f) - m * m + EPSF);
    float* op = xn + (size_t)pix * DIMC;
    op[lane] = (a0 - m) * inv * g[lane] + bt[lane];
    if (lane < 32) op[lane + 64] = (a1 - m) * inv * g[lane + 64] + bt[lane + 64];
}

// ---------- 2. in_proj GEMM ----------
__global__ __launch_bounds__(384) void gemm1_k(const float* __restrict__ xn,
                                               const float* __restrict__ W,
                                               float* __restrict__ xcr,
                                               float* __restrict__ zs) {
    __shared__ float xs[8][96];
    int row0 = blockIdx.x * 8;
    for (int i = threadIdx.x; i < 768; i += 384) xs[i / 96][i % 96] = xn[(size_t)row0 * 96 + i];
    __syncthreads();
    int col = threadIdx.x;  // 0..383
    const float* wr = W + (size_t)col * DIMC;
    float acc[8] = {0, 0, 0, 0, 0, 0, 0, 0};
    for (int c0 = 0; c0 < 96; c0 += 4) {
        float4 wv = *(const float4*)(wr + c0);
#pragma unroll
        for (int r = 0; r < 8; ++r) {
            float4 xv = *(const float4*)(&xs[r][c0]);
            acc[r] = fmaf(xv.x, wv.x, acc[r]);
            acc[r] = fmaf(xv.y, wv.y, acc[r]);
            acc[r] = fmaf(xv.z, wv.z, acc[r]);
            acc[r] = fmaf(xv.w, wv.w, acc[r]);
        }
    }
#pragma unroll
    for (int r = 0; r < 8; ++r) {
        int row = row0 + r, b = row / LL, pos = row % LL;
        if (col < DINC) xcr[((size_t)b * DINC + col) * LL + pos] = acc[r];
        else            zs[(size_t)row * DINC + (col - DINC)] = siluf(acc[r]);
    }
}

// ---------- 3. depthwise 3x3 conv + bias + silu ----------
__global__ __launch_bounds__(256) void dwconv_k(const float* __restrict__ xcr,
                                                const float* __restrict__ cw,
                                                const float* __restrict__ cb,
                                                float* __restrict__ xconv) {
    int i = blockIdx.x * 256 + threadIdx.x;
    int pos = i % LL, d = (i / LL) % DINC, b = i / (LL * DINC);
    int hh = pos / WWD, ww = pos % WWD;
    const float* src = xcr + ((size_t)b * DINC + d) * LL;
    const float* wk = cw + d * 9;
    float acc = cb[d];
#pragma unroll
    for (int ky = 0; ky < 3; ++ky) {
        int y = hh + ky - 1;
        if ((unsigned)y >= HH) continue;
#pragma unroll
        for (int kx = 0; kx < 3; ++kx) {
            int xq = ww + kx - 1;
            if ((unsigned)xq >= WWD) continue;
            acc = fmaf(wk[ky * 3 + kx], src[y * WWD + xq], acc);
        }
    }
    xconv[i] = siluf(acc);
}

// ---------- 4. x_proj ----------
__global__ __launch_bounds__(256) void xdbl_k(const float* __restrict__ xconv,
                                              const float* __restrict__ xpw,
                                              float* __restrict__ dts,
                                              float* __restrict__ bc) {
    int g = blockIdx.x * 4 + (threadIdx.x >> 6);
    int lane = threadIdx.x & 63;
    int l = g % LL, k = (g / LL) % KDIR, b = g / (LL * KDIR);
    int pos = pos_of_l(k, l);
    const float* xc = xconv + (size_t)b * DINC * LL + pos;
    bool act = lane < 38;
    const float* wp = xpw + ((size_t)k * 38 + (act ? lane : 0)) * DINC;
    float acc = 0.f;
#pragma unroll 8
    for (int dd = 0; dd < DINC; ++dd) {
        float xv = xc[(size_t)dd * LL];
        acc = fmaf(wp[dd], xv, acc);
    }
    size_t rb = (size_t)(b * KDIR + k) * LL + l;
    if (lane < DTRC)      dts[rb * DTRC + lane] = acc;
    else if (lane < 22)   bc[(rb * NSTC + (lane - 6)) * 2 + 0] = acc;
    else if (lane < 38)   bc[(rb * NSTC + (lane - 22)) * 2 + 1] = acc;
}

// ---------- 5. delta pack ----------
__global__ __launch_bounds__(256) void dpack_k(const float* __restrict__ dts,
                                               const float* __restrict__ xconv,
                                               const float* __restrict__ dtw,
                                               const float* __restrict__ dtb,
                                               float2* __restrict__ dpk) {
    int i = blockIdx.x * 256 + threadIdx.x;
    int l = i % LL, d = (i / LL) % DINC, k = (i / (LL * DINC)) % KDIR, b = i / (LL * DINC * KDIR);
    int pos = pos_of_l(k, l);
    const float* dr = dts + ((size_t)(b * KDIR + k) * LL + l) * DTRC;
    const float* wr = dtw + ((size_t)k * DINC + d) * DTRC;
    float acc = dtb[k * DINC + d];
#pragma unroll
    for (int r = 0; r < DTRC; ++r) acc = fmaf(wr[r], dr[r], acc);
    float dv = softplusf(acc);
    float xv = xconv[((size_t)b * DINC + d) * LL + pos];
    dpk[i] = make_float2(dv, dv * xv);
}

// ---------- 6a. scan phase 1: per-chunk local scan -> h_end + sum(delta) ----------
__global__ __launch_bounds__(256) void scan1_k(const float2* __restrict__ dpk,
                                               const float2* __restrict__ bc,
                                               const float* __restrict__ alog,
                                               float* __restrict__ hend,
                                               float* __restrict__ sumd) {
    int gid = blockIdx.x * 16 + (threadIdx.x >> 4);  // chain*NCH + c
    int lane = threadIdx.x & 15;
    int chain = gid / NCH, c = gid % NCH;
    float An = -__expf(alog[(size_t)(chain % (KDIR * DINC)) * NSTC + lane]);
    const float2* dpr = dpk + (size_t)chain * LL + c * LC;
    const float2* bcr = bc + ((size_t)(chain / DINC) * LL + c * LC) * NSTC + lane;
    float h = 0.f, sd = 0.f;
#pragma unroll 4
    for (int l = 0; l < LC; ++l) {
        float2 dpv = dpr[l];
        float2 bcv = bcr[(size_t)l * NSTC];
        sd += dpv.x;
        h = fmaf(__expf(dpv.x * An), h, dpv.y * bcv.x);
    }
    hend[(size_t)gid * NSTC + lane] = h;
    if (lane == 0) sumd[gid] = sd;
}

// ---------- 6b. scan phase 2: sequential combine over chunks (in place: hend -> hpre) ----------
__global__ __launch_bounds__(256) void scan2_k(float* __restrict__ hend,
                                               const float* __restrict__ sumd,
                                               const float* __restrict__ alog) {
    int chain = blockIdx.x * 16 + (threadIdx.x >> 4);
    int lane = threadIdx.x & 15;
    float An = -__expf(alog[(size_t)(chain % (KDIR * DINC)) * NSTC + lane]);
    float* hp = hend + (size_t)chain * NCH * NSTC + lane;
    const float* sp = sumd + (size_t)chain * NCH;
    float h = 0.f;
    for (int c = 0; c < NCH; ++c) {
        float he = hp[(size_t)c * NSTC];
        float sd = sp[c];
        hp[(size_t)c * NSTC] = h;           // h_pre for chunk c
        h = fmaf(__expf(An * sd), h, he);
    }
}

// ---------- 6c. scan phase 3: local scan with h0 = h_pre, emit y ----------
__global__ __launch_bounds__(256) void scan3_k(const float2* __restrict__ dpk,
                                               const float2* __restrict__ bc,
                                               const float* __restrict__ alog,
                                               const float* __restrict__ hpre,
                                               float* __restrict__ ys) {
    int gid = blockIdx.x * 16 + (threadIdx.x >> 4);  // chain*NCH + c
    int lane = threadIdx.x & 15;
    int chain = gid / NCH, c = gid % NCH;
    float An = -__expf(alog[(size_t)(chain % (KDIR * DINC)) * NSTC + lane]);
    const float2* dpr = dpk + (size_t)chain * LL + c * LC;
    const float2* bcr = bc + ((size_t)(chain / DINC) * LL + c * LC) * NSTC + lane;
    float* yr = ys + (size_t)chain * LL + c * LC;
    float h = hpre[(size_t)gid * NSTC + lane];
#pragma unroll 4
    for (int l = 0; l < LC; ++l) {
        float2 dpv = dpr[l];
        float2 bcv = bcr[(size_t)l * NSTC];
        h = fmaf(__expf(dpv.x * An), h, dpv.y * bcv.x);
        float p = h * bcv.y;
        p += __shfl_xor(p, 1, 16);
        p += __shfl_xor(p, 2, 16);
        p += __shfl_xor(p, 4, 16);
        p += __shfl_xor(p, 8, 16);
        if (lane == 0) yr[l] = p;
    }
}

// ---------- 7. combine 4 directions (+ D*x term) -> y_t NCHW ----------
__global__ __launch_bounds__(256) void combine_k(const float* __restrict__ ys,
                                                 const float* __restrict__ xconv,
                                                 const float* __restrict__ dsv,
                                                 float* __restrict__ yt) {
    int i = blockIdx.x * 256 + threadIdx.x;
    int pos = i % LL, d = (i / LL) % DINC, b = i / (LL * DINC);
    int h = pos / WWD, w = pos % WWD;
    int l1 = w * HH + h;
    size_t c0 = ((size_t)(b * KDIR + 0) * DINC + d) * LL;
    size_t c1 = ((size_t)(b * KDIR + 1) * DINC + d) * LL;
    size_t c2 = ((size_t)(b * KDIR + 2) * DINC + d) * LL;
    size_t c3 = ((size_t)(b * KDIR + 3) * DINC + d) * LL;
    float y = ys[c0 + pos] + ys[c1 + l1] + ys[c2 + (LL - 1 - pos)] + ys[c3 + (LL - 1 - l1)];
    float sumD = dsv[d] + dsv[DINC + d] + dsv[2 * DINC + d] + dsv[3 * DINC + d];
    y = fmaf(xconv[((size_t)b * DINC + d) * LL + pos], sumD, y);
    yt[i] = y;
}

// ---------- 8. out_norm LN over 192 * silu(z) ----------
__global__ __launch_bounds__(256) void lnmul_k(const float* __restrict__ yt,
                                               const float* __restrict__ g,
                                               const float* __restrict__ bt,
                                               const float* __restrict__ zs,
                                               float* __restrict__ yact) {
    int pix = blockIdx.x * 4 + (threadIdx.x >> 6);
    int lane = threadIdx.x & 63;
    int b = pix / LL, pos = pix % LL;
    const float* yp = yt + (size_t)b * DINC * LL + pos;
    float v0 = yp[(size_t)lane * LL];
    float v1 = yp[(size_t)(lane + 64) * LL];
    float v2 = yp[(size_t)(lane + 128) * LL];
    float s = v0 + v1 + v2, q = v0 * v0 + v1 * v1 + v2 * v2;
    for (int o = 32; o; o >>= 1) { s += __shfl_xor(s, o, 64); q += __shfl_xor(q, o, 64); }
    float m = s * (1.f / 192.f);
    float inv = rsqrtf(q * (1.f / 192.f) - m * m + EPSF);
    float* op = yact + (size_t)pix * DINC;
    const float* zp = zs + (size_t)pix * DINC;
    op[lane] = ((v0 - m) * inv * g[lane] + bt[lane]) * zp[lane];
    op[lane + 64] = ((v1 - m) * inv * g[lane + 64] + bt[lane + 64]) * zp[lane + 64];
    op[lane + 128] = ((v2 - m) * inv * g[lane + 128] + bt[lane + 128]) * zp[lane + 128];
}

// ---------- 9. out_proj GEMM + scaled residual ----------
__global__ __launch_bounds__(384) void gemm2_k(const float* __restrict__ yact,
                                               const float* __restrict__ opw,
                                               const float* __restrict__ x,
                                               const float* __restrict__ sc1,
                                               float* __restrict__ vl) {
    __shared__ float ysl[16][192];
    int row0 = blockIdx.x * 16;
    for (int i = threadIdx.x; i < 16 * 192; i += 384)
        ysl[i / 192][i % 192] = yact[(size_t)row0 * DINC + i];
    __syncthreads();
    int col = threadIdx.x % 96;
    int rs = threadIdx.x / 96;
    const float* wr = opw + (size_t)col * DINC;
    float acc[4] = {0, 0, 0, 0};
    for (int c0 = 0; c0 < DINC; c0 += 4) {
        float4 wv = *(const float4*)(wr + c0);
#pragma unroll
        for (int i = 0; i < 4; ++i) {
            float4 xv = *(const float4*)(&ysl[rs + 4 * i][c0]);
            acc[i] = fmaf(xv.x, wv.x, acc[i]);
            acc[i] = fmaf(xv.y, wv.y, acc[i]);
            acc[i] = fmaf(xv.z, wv.z, acc[i]);
            acc[i] = fmaf(xv.w, wv.w, acc[i]);
        }
    }
#pragma unroll
    for (int i = 0; i < 4; ++i) {
        int row = row0 + rs + 4 * i, b = row / LL, pos = row % LL;
        float v = fmaf(sc1[col], x[((size_t)b * DIMC + col) * LL + pos], acc[i]);
        vl[(size_t)row * DIMC + col] = v;
    }
}

// ---------- 10. LN2 + conv1x1(96->24) + BN + ReLU ----------
__global__ __launch_bounds__(256) void ln2conv1_k(const float* __restrict__ vl,
                                                  const float* __restrict__ g,
                                                  const float* __restrict__ bt,
                                                  const float* __restrict__ w1,
                                                  const float* __restrict__ g1,
                                                  const float* __restrict__ b1,
                                                  const float* __restrict__ m1,
                                                  const float* __restrict__ v1,
                                                  float* __restrict__ h1) {
    __shared__ float row[4][96];
    int wv = threadIdx.x >> 6, lane = threadIdx.x & 63;
    int pix = blockIdx.x * 4 + wv;
    const float* vr = vl + (size_t)pix * DIMC;
    float a0 = vr[lane];
    float a1 = (lane < 32) ? vr[64 + lane] : 0.f;
    float s = a0 + a1, q = a0 * a0 + a1 * a1;
    for (int o = 32; o; o >>= 1) { s += __shfl_xor(s, o, 64); q += __shfl_xor(q, o, 64); }
    float m = s * (1.f / 96.f);
    float inv = rsqrtf(q * (1.f / 96.f) - m * m + EPSF);
    row[wv][lane] = (a0 - m) * inv * g[lane] + bt[lane];
    if (lane < 32) row[wv][64 + lane] = (a1 - m) * inv * g[64 + lane] + bt[64 + lane];
    __syncthreads();
    if (lane < 24) {
        const float* wr = w1 + lane * 96;
        float acc = 0.f;
#pragma unroll 8
        for (int c = 0; c < 96; ++c) acc = fmaf(row[wv][c], wr[c], acc);
        float bn = (acc - m1[lane]) * rsqrtf(v1[lane] + EPSF) * g1[lane] + b1[lane];
        int b = pix / LL, pos = pix % LL;
        h1[((size_t)b * 24 + lane) * LL + pos] = fmaxf(bn, 0.f);
    }
}

// ---------- 11. conv3x3 (24->24) + BN + ReLU ----------
__global__ __launch_bounds__(256) void conv2_k(const float* __restrict__ h1,
                                               const float* __restrict__ w2,
                                               const float* __restrict__ g2,
                                               const float* __restrict__ b2,
                                               const float* __restrict__ m2,
                                               const float* __restrict__ v2,
                                               float* __restrict__ h2) {
    int i = blockIdx.x * 256 + threadIdx.x;
    int pos = i % LL, mo = (i / LL) % 24, b = i / (LL * 24);
    int hh = pos / WWD, ww = pos % WWD;
    float acc = 0.f;
    for (int c = 0; c < 24; ++c) {
        const float* src = h1 + ((size_t)b * 24 + c) * LL;
        const float* wk = w2 + ((size_t)(mo * 24 + c)) * 9;
#pragma unroll
        for (int ky = 0; ky < 3; ++ky) {
            int y = hh + ky - 1;
            if ((unsigned)y >= HH) continue;
#pragma unroll
            for (int kx = 0; kx < 3; ++kx) {
                int xq = ww + kx - 1;
                if ((unsigned)xq >= WWD) continue;
                acc = fmaf(wk[ky * 3 + kx], src[y * WWD + xq], acc);
            }
        }
    }
    float bn = (acc - m2[mo]) * rsqrtf(v2[mo] + EPSF) * g2[mo] + b2[mo];
    h2[i] = fmaxf(bn, 0.f);
}

// ---------- 12. conv1x1 (24->96) + BN ----------
__global__ __launch_bounds__(256) void conv3_k(const float* __restrict__ h2,
                                               const float* __restrict__ w3,
                                               const float* __restrict__ g3,
                                               const float* __restrict__ b3,
                                               const float* __restrict__ m3,
                                               const float* __restrict__ v3,
                                               float* __restrict__ h3) {
    int i = blockIdx.x * 256 + threadIdx.x;
    int pos = i % LL, c = (i / LL) % DIMC, b = i / (LL * DIMC);
    const float* wr = w3 + c * 24;
    float acc = 0.f;
#pragma unroll
    for (int mo = 0; mo < 24; ++mo)
        acc = fmaf(wr[mo], h2[((size_t)b * 24 + mo) * LL + pos], acc);
    h3[i] = (acc - m3[c]) * rsqrtf(v3[c] + EPSF) * g3[c] + b3[c];
}

// ---------- 13. SE pool ----------
__global__ __launch_bounds__(256) void pool_k(const float* __restrict__ h3,
                                              float* __restrict__ pooled) {
    int bc = blockIdx.x;
    const float* p = h3 + (size_t)bc * LL;
    float s = 0.f;
    for (int i = threadIdx.x; i < LL; i += 256) s += p[i];
    for (int o = 32; o; o >>= 1) s += __shfl_xor(s, o, 64);
    __shared__ float wsum[4];
    if ((threadIdx.x & 63) == 0) wsum[threadIdx.x >> 6] = s;
    __syncthreads();
    if (threadIdx.x == 0) pooled[bc] = (wsum[0] + wsum[1] + wsum[2] + wsum[3]) * (1.f / 3136.f);
}

// ---------- 14. SE MLP ----------
__global__ __launch_bounds__(128) void semlp_k(const float* __restrict__ pooled,
                                               const float* __restrict__ sw1,
                                               const float* __restrict__ sw2,
                                               float* __restrict__ sew) {
    __shared__ float pl[2][96];
    __shared__ float hid[2][24];
    for (int i = threadIdx.x; i < 192; i += 128) pl[i / 96][i % 96] = pooled[i];
    __syncthreads();
    if (threadIdx.x < 48) {
        int b = threadIdx.x / 24, mo = threadIdx.x % 24;
        float acc = 0.f;
        for (int c = 0; c < 96; ++c) acc = fmaf(pl[b][c], sw1[mo * 96 + c], acc);
        hid[b][mo] = fmaxf(acc, 0.f);
    }
    __syncthreads();
    for (int i = threadIdx.x; i < 192; i += 128) {
        int b = i / 96, c = i % 96;
        float acc = 0.f;
        for (int mo = 0; mo < 24; ++mo) acc = fmaf(hid[b][mo], sw2[c * 24 + mo], acc);
        sew[i] = 1.f / (1.f + __expf(-acc));
    }
}

// ---------- 15. final ----------
__global__ __launch_bounds__(256) void final_k(const float* __restrict__ h3,
                                               const float* __restrict__ sew,
                                               const float* __restrict__ vl,
                                               const float* __restrict__ sc2,
                                               float* __restrict__ out) {
    int i = blockIdx.x * 256 + threadIdx.x;
    int pos = i % LL, c = (i / LL) % DIMC, b = i / (LL * DIMC);
    out[i] = fmaf(h3[i], sew[b * DIMC + c],
                  sc2[c] * vl[((size_t)b * LL + pos) * DIMC + c]);
}

extern "C" void kernel_launch(void* const* d_in, const int* in_sizes, int n_in,
                              void* d_out, int out_size, void* d_ws, size_t ws_size,
                              hipStream_t stream) {
    const float* x    = (const float*)d_in[0];
    const float* n1g  = (const float*)d_in[1];
    const float* n1b  = (const float*)d_in[2];
    const float* ipw  = (const float*)d_in[3];
    const float* cw   = (const float*)d_in[4];
    const float* cb   = (const float*)d_in[5];
    const float* xpw  = (const float*)d_in[6];
    const float* dtw  = (const float*)d_in[7];
    const float* dtb  = (const float*)d_in[8];
    const float* alog = (const float*)d_in[9];
    const float* dsv  = (const float*)d_in[10];
    const float* ong  = (const float*)d_in[11];
    const float* onb  = (const float*)d_in[12];
    const float* opw  = (const float*)d_in[13];
    const float* sc1  = (const float*)d_in[14];
    const float* n2g  = (const float*)d_in[15];
    const float* n2b  = (const float*)d_in[16];
    const float* w1   = (const float*)d_in[17];
    const float* g1   = (const float*)d_in[18];
    const float* b1   = (const float*)d_in[19];
    const float* m1   = (const float*)d_in[20];
    const float* v1   = (const float*)d_in[21];
    const float* w2   = (const float*)d_in[22];
    const float* g2   = (const float*)d_in[23];
    const float* b2   = (const float*)d_in[24];
    const float* m2   = (const float*)d_in[25];
    const float* v2   = (const float*)d_in[26];
    const float* w3   = (const float*)d_in[27];
    const float* g3   = (const float*)d_in[28];
    const float* b3   = (const float*)d_in[29];
    const float* m3   = (const float*)d_in[30];
    const float* v3   = (const float*)d_in[31];
    const float* sw1  = (const float*)d_in[32];
    const float* sw2  = (const float*)d_in[33];
    const float* sc2  = (const float*)d_in[34];
    float* ws = (float*)d_ws;
    float* out = (float*)d_out;

    ln1_k<<<NPIX / 4, 256, 0, stream>>>(x, n1g, n1b, ws + OFF_XN);
    gemm1_k<<<NPIX / 8, 384, 0, stream>>>(ws + OFF_XN, ipw, ws + OFF_XCRAW, ws + OFF_ZS);
    dwconv_k<<<(BB * DINC * LL) / 256, 256, 0, stream>>>(ws + OFF_XCRAW, cw, cb, ws + OFF_XCONV);
    xdbl_k<<<(BB * KDIR * LL) / 4, 256, 0, stream>>>(ws + OFF_XCONV, xpw, ws + OFF_DTS, ws + OFF_BC);
    dpack_k<<<(BB * KDIR * DINC * LL) / 256, 256, 0, stream>>>(
        ws + OFF_DTS, ws + OFF_XCONV, dtw, dtb, (float2*)(ws + OFF_DPACK));

    // chunked selective scan (3 phases)
    scan1_k<<<(NCHAIN * NCH) / 16, 256, 0, stream>>>(
        (const float2*)(ws + OFF_DPACK), (const float2*)(ws + OFF_BC), alog,
        ws + OFF_HEND, ws + OFF_SUMD);
    scan2_k<<<NCHAIN / 16, 256, 0, stream>>>(ws + OFF_HEND, ws + OFF_SUMD, alog);
    scan3_k<<<(NCHAIN * NCH) / 16, 256, 0, stream>>>(
        (const float2*)(ws + OFF_DPACK), (const float2*)(ws + OFF_BC), alog,
        ws + OFF_HEND, ws + OFF_YS);

    combine_k<<<(BB * DINC * LL) / 256, 256, 0, stream>>>(ws + OFF_YS, ws + OFF_XCONV, dsv,
                                                          ws + OFF_YT);
    lnmul_k<<<NPIX / 4, 256, 0, stream>>>(ws + OFF_YT, ong, onb, ws + OFF_ZS, ws + OFF_YACT);
    gemm2_k<<<NPIX / 16, 384, 0, stream>>>(ws + OFF_YACT, opw, x, sc1, ws + OFF_VL);
    ln2conv1_k<<<NPIX / 4, 256, 0, stream>>>(ws + OFF_VL, n2g, n2b, w1, g1, b1, m1, v1,
                                             ws + OFF_H1);
    conv2_k<<<(BB * 24 * LL) / 256, 256, 0, stream>>>(ws + OFF_H1, w2, g2, b2, m2, v2,
                                                      ws + OFF_H2);
    conv3_k<<<(BB * DIMC * LL) / 256, 256, 0, stream>>>(ws + OFF_H2, w3, g3, b3, m3, v3,
                                                        ws + OFF_H3);
    pool_k<<<BB * DIMC, 256, 0, stream>>>(ws + OFF_H3, ws + OFF_POOL);
    semlp_k<<<1, 128, 0, stream>>>(ws + OFF_POOL, sw1, sw2, ws + OFF_SEW);
    final_k<<<(BB * DIMC * LL) / 256, 256, 0, stream>>>(ws + OFF_H3, ws + OFF_SEW, ws + OFF_VL,
                                                        sc2, out);
    (void)in_sizes; (void)n_in; (void)out_size; (void)ws_size;
}

// Round 3
// 446.005 us; speedup vs baseline: 4.0435x; 1.7991x over previous
//
#include <hip/hip_runtime.h>
#include <math.h>

#define DIMC 96
#define DINC 192
#define NSTC 16
#define DTRC 6
#define KDIR 4
#define BB   2
#define HH   56
#define WWD  56
#define LL   3136            // HH*WWD
#define NPIX (BB*LL)         // 6272
#define EPSF 1e-5f
#define NCH  49              // chunks per chain
#define LC   64              // chunk length (49*64 = 3136)
#define NCHAIN (BB*KDIR*DINC)  // 1536
#define PADK 100             // LDS row stride (floats): 16B-aligned, <=2-way banks

// ---------- workspace layout (float offsets) ----------
#define OFF_XN     0u          // 602112   xn (B,L,96); sumd during scan; H3 later
#define OFF_XCRAW  602112u     // 1204224  xc pre-conv NCHW; hend/hpre during scan; y_t after
#define OFF_ZS     1806336u    // 1204224  silu(z) (B,L,192)
#define OFF_XCONV  3010560u    // 1204224  silu(conv(xc)) NCHW; yact after combine
#define OFF_DTS    4214784u    // 150528   dts (B,K,L,6)
#define OFF_BC     4365312u    // 802816   interleaved (B,K,L,16,{B,C})
#define OFF_DPACK  5168128u    // 9633792  (B,K,192,L) float2 {delta, delta*x}
#define OFF_YS     14801920u   // 4816896  ys (B,K,192,L) in scan order l
#define OFF_HEND   OFF_XCRAW   // 1536*49*16 = 1204224 floats exactly
#define OFF_SUMD   OFF_XN      // 1536*49 = 75264 floats
#define OFF_YT     OFF_XCRAW
#define OFF_YACT   OFF_XCONV
#define OFF_VL     OFF_DPACK               // 602112
#define OFF_H1     (OFF_DPACK + 1000000u)  // 150528
#define OFF_H2     (OFF_DPACK + 1200000u)  // 150528
#define OFF_H3     OFF_XN                  // 602112
#define OFF_POOL   (OFF_DPACK + 1400000u)  // 192
#define OFF_SEW    (OFF_DPACK + 1400448u)  // 192

__device__ __forceinline__ float siluf(float x) { return x / (1.f + __expf(-x)); }
__device__ __forceinline__ float softplusf(float x) {
    return fmaxf(x, 0.f) + log1pf(__expf(-fabsf(x)));
}
__device__ __forceinline__ int pos_of_l(int k, int l) {
    if (k == 0) return l;
    if (k == 1) return (l % HH) * WWD + (l / HH);
    if (k == 2) return LL - 1 - l;
    int lp = LL - 1 - l;
    return (lp % HH) * WWD + (lp / HH);
}

// ---------- 1. LN over C=96 of NCHW input -> xn (B,L,96) ----------
__global__ __launch_bounds__(256) void ln1_k(const float* __restrict__ x,
                                             const float* __restrict__ g,
                                             const float* __restrict__ bt,
                                             float* __restrict__ xn) {
    int pix = blockIdx.x * 4 + (threadIdx.x >> 6);
    int lane = threadIdx.x & 63;
    int b = pix / LL, pos = pix % LL;
    const float* xp = x + (size_t)b * DIMC * LL + pos;
    float a0 = xp[(size_t)lane * LL];
    float a1 = (lane < 32) ? xp[(size_t)(lane + 64) * LL] : 0.f;
    float s = a0 + a1, q = a0 * a0 + a1 * a1;
    for (int o = 32; o; o >>= 1) { s += __shfl_xor(s, o, 64); q += __shfl_xor(q, o, 64); }
    float m = s * (1.f / 96.f);
    float inv = rsqrtf(q * (1.f / 96.f) - m * m + EPSF);
    float* op = xn + (size_t)pix * DIMC;
    op[lane] = (a0 - m) * inv * g[lane] + bt[lane];
    if (lane < 32) op[lane + 64] = (a1 - m) * inv * g[lane + 64] + bt[lane + 64];
}

// ---------- 2. in_proj GEMM: LDS-tiled, M=64 N=96 K=96 ----------
// grid (98, 4): blockIdx.y selects 96-col band of the 384 outputs.
__global__ __launch_bounds__(256) void gemm1_k(const float* __restrict__ xn,
                                               const float* __restrict__ W,
                                               float* __restrict__ xcr,
                                               float* __restrict__ zs) {
    __shared__ float xT[64 * PADK];
    __shared__ float wT[96 * PADK];
    int row0 = blockIdx.x * 64;
    int c0 = blockIdx.y * 96;
    // stage xn tile (contiguous 64x96 block) via float4
    const float4* xg = (const float4*)(xn + (size_t)row0 * 96);
    for (int i = threadIdx.x; i < 1536; i += 256) {
        int f = i * 4, r = f / 96, k = f % 96;
        *(float4*)&xT[r * PADK + k] = xg[i];
    }
    // stage W tile (contiguous 96x96 block of row-major (384,96))
    const float4* wg = (const float4*)(W + (size_t)c0 * 96);
    for (int i = threadIdx.x; i < 2304; i += 256) {
        int f = i * 4, r = f / 96, k = f % 96;
        *(float4*)&wT[r * PADK + k] = wg[i];
    }
    __syncthreads();
    int tc = threadIdx.x & 15;   // col group: cols tc+16j
    int tr = threadIdx.x >> 4;   // row group: rows tr*4+i
    float acc[4][6] = {};
    for (int k = 0; k < 96; ++k) {
        float xv[4], wv[6];
#pragma unroll
        for (int i = 0; i < 4; ++i) xv[i] = xT[(tr * 4 + i) * PADK + k];
#pragma unroll
        for (int j = 0; j < 6; ++j) wv[j] = wT[(tc + 16 * j) * PADK + k];
#pragma unroll
        for (int i = 0; i < 4; ++i)
#pragma unroll
            for (int j = 0; j < 6; ++j) acc[i][j] = fmaf(xv[i], wv[j], acc[i][j]);
    }
    int row = row0 + tr * 4;           // 4 consecutive rows, 4-aligned, no b-crossing
    int b = row / LL, pos = row % LL;
    if (c0 < DINC) {
        // xcr NCHW: per col, 4 consecutive pos -> one aligned float4 store
#pragma unroll
        for (int j = 0; j < 6; ++j) {
            int col = c0 + tc + 16 * j;
            float4 v = make_float4(acc[0][j], acc[1][j], acc[2][j], acc[3][j]);
            *(float4*)&xcr[((size_t)b * DINC + col) * LL + pos] = v;
        }
    } else {
#pragma unroll
        for (int i = 0; i < 4; ++i)
#pragma unroll
            for (int j = 0; j < 6; ++j) {
                int zc = c0 - DINC + tc + 16 * j;
                zs[(size_t)(row + i) * DINC + zc] = siluf(acc[i][j]);
            }
    }
}

// ---------- 3. depthwise 3x3 conv + bias + silu ----------
__global__ __launch_bounds__(256) void dwconv_k(const float* __restrict__ xcr,
                                                const float* __restrict__ cw,
                                                const float* __restrict__ cb,
                                                float* __restrict__ xconv) {
    int i = blockIdx.x * 256 + threadIdx.x;
    int pos = i % LL, d = (i / LL) % DINC, b = i / (LL * DINC);
    int hh = pos / WWD, ww = pos % WWD;
    const float* src = xcr + ((size_t)b * DINC + d) * LL;
    const float* wk = cw + d * 9;
    float acc = cb[d];
#pragma unroll
    for (int ky = 0; ky < 3; ++ky) {
        int y = hh + ky - 1;
        if ((unsigned)y >= HH) continue;
#pragma unroll
        for (int kx = 0; kx < 3; ++kx) {
            int xq = ww + kx - 1;
            if ((unsigned)xq >= WWD) continue;
            acc = fmaf(wk[ky * 3 + kx], src[y * WWD + xq], acc);
        }
    }
    xconv[i] = siluf(acc);
}

// ---------- 4. x_proj ----------
__global__ __launch_bounds__(256) void xdbl_k(const float* __restrict__ xconv,
                                              const float* __restrict__ xpw,
                                              float* __restrict__ dts,
                                              float* __restrict__ bc) {
    int g = blockIdx.x * 4 + (threadIdx.x >> 6);
    int lane = threadIdx.x & 63;
    int l = g % LL, k = (g / LL) % KDIR, b = g / (LL * KDIR);
    int pos = pos_of_l(k, l);
    const float* xc = xconv + (size_t)b * DINC * LL + pos;
    bool act = lane < 38;
    const float* wp = xpw + ((size_t)k * 38 + (act ? lane : 0)) * DINC;
    float acc = 0.f;
#pragma unroll 8
    for (int dd = 0; dd < DINC; ++dd) {
        float xv = xc[(size_t)dd * LL];
        acc = fmaf(wp[dd], xv, acc);
    }
    size_t rb = (size_t)(b * KDIR + k) * LL + l;
    if (lane < DTRC)      dts[rb * DTRC + lane] = acc;
    else if (lane < 22)   bc[(rb * NSTC + (lane - 6)) * 2 + 0] = acc;
    else if (lane < 38)   bc[(rb * NSTC + (lane - 22)) * 2 + 1] = acc;
}

// ---------- 5. delta pack ----------
__global__ __launch_bounds__(256) void dpack_k(const float* __restrict__ dts,
                                               const float* __restrict__ xconv,
                                               const float* __restrict__ dtw,
                                               const float* __restrict__ dtb,
                                               float2* __restrict__ dpk) {
    int i = blockIdx.x * 256 + threadIdx.x;
    int l = i % LL, d = (i / LL) % DINC, k = (i / (LL * DINC)) % KDIR, b = i / (LL * DINC * KDIR);
    int pos = pos_of_l(k, l);
    const float* dr = dts + ((size_t)(b * KDIR + k) * LL + l) * DTRC;
    const float* wr = dtw + ((size_t)k * DINC + d) * DTRC;
    float acc = dtb[k * DINC + d];
#pragma unroll
    for (int r = 0; r < DTRC; ++r) acc = fmaf(wr[r], dr[r], acc);
    float dv = softplusf(acc);
    float xv = xconv[((size_t)b * DINC + d) * LL + pos];
    dpk[i] = make_float2(dv, dv * xv);
}

// ---------- 6a. scan phase 1 ----------
__global__ __launch_bounds__(256) void scan1_k(const float2* __restrict__ dpk,
                                               const float2* __restrict__ bc,
                                               const float* __restrict__ alog,
                                               float* __restrict__ hend,
                                               float* __restrict__ sumd) {
    int gid = blockIdx.x * 16 + (threadIdx.x >> 4);
    int lane = threadIdx.x & 15;
    int chain = gid / NCH, c = gid % NCH;
    float An = -__expf(alog[(size_t)(chain % (KDIR * DINC)) * NSTC + lane]);
    const float2* dpr = dpk + (size_t)chain * LL + c * LC;
    const float2* bcr = bc + ((size_t)(chain / DINC) * LL + c * LC) * NSTC + lane;
    float h = 0.f, sd = 0.f;
#pragma unroll 4
    for (int l = 0; l < LC; ++l) {
        float2 dpv = dpr[l];
        float2 bcv = bcr[(size_t)l * NSTC];
        sd += dpv.x;
        h = fmaf(__expf(dpv.x * An), h, dpv.y * bcv.x);
    }
    hend[(size_t)gid * NSTC + lane] = h;
    if (lane == 0) sumd[gid] = sd;
}

// ---------- 6b. scan phase 2 ----------
__global__ __launch_bounds__(256) void scan2_k(float* __restrict__ hend,
                                               const float* __restrict__ sumd,
                                               const float* __restrict__ alog) {
    int chain = blockIdx.x * 16 + (threadIdx.x >> 4);
    int lane = threadIdx.x & 15;
    float An = -__expf(alog[(size_t)(chain % (KDIR * DINC)) * NSTC + lane]);
    float* hp = hend + (size_t)chain * NCH * NSTC + lane;
    const float* sp = sumd + (size_t)chain * NCH;
    float h = 0.f;
    for (int c = 0; c < NCH; ++c) {
        float he = hp[(size_t)c * NSTC];
        float sd = sp[c];
        hp[(size_t)c * NSTC] = h;
        h = fmaf(__expf(An * sd), h, he);
    }
}

// ---------- 6c. scan phase 3 ----------
__global__ __launch_bounds__(256) void scan3_k(const float2* __restrict__ dpk,
                                               const float2* __restrict__ bc,
                                               const float* __restrict__ alog,
                                               const float* __restrict__ hpre,
                                               float* __restrict__ ys) {
    int gid = blockIdx.x * 16 + (threadIdx.x >> 4);
    int lane = threadIdx.x & 15;
    int chain = gid / NCH, c = gid % NCH;
    float An = -__expf(alog[(size_t)(chain % (KDIR * DINC)) * NSTC + lane]);
    const float2* dpr = dpk + (size_t)chain * LL + c * LC;
    const float2* bcr = bc + ((size_t)(chain / DINC) * LL + c * LC) * NSTC + lane;
    float* yr = ys + (size_t)chain * LL + c * LC;
    float h = hpre[(size_t)gid * NSTC + lane];
#pragma unroll 4
    for (int l = 0; l < LC; ++l) {
        float2 dpv = dpr[l];
        float2 bcv = bcr[(size_t)l * NSTC];
        h = fmaf(__expf(dpv.x * An), h, dpv.y * bcv.x);
        float p = h * bcv.y;
        p += __shfl_xor(p, 1, 16);
        p += __shfl_xor(p, 2, 16);
        p += __shfl_xor(p, 4, 16);
        p += __shfl_xor(p, 8, 16);
        if (lane == 0) yr[l] = p;
    }
}

// ---------- 7. combine 4 directions (+ D*x term) -> y_t NCHW ----------
__global__ __launch_bounds__(256) void combine_k(const float* __restrict__ ys,
                                                 const float* __restrict__ xconv,
                                                 const float* __restrict__ dsv,
                                                 float* __restrict__ yt) {
    int i = blockIdx.x * 256 + threadIdx.x;
    int pos = i % LL, d = (i / LL) % DINC, b = i / (LL * DINC);
    int h = pos / WWD, w = pos % WWD;
    int l1 = w * HH + h;
    size_t c0 = ((size_t)(b * KDIR + 0) * DINC + d) * LL;
    size_t c1 = ((size_t)(b * KDIR + 1) * DINC + d) * LL;
    size_t c2 = ((size_t)(b * KDIR + 2) * DINC + d) * LL;
    size_t c3 = ((size_t)(b * KDIR + 3) * DINC + d) * LL;
    float y = ys[c0 + pos] + ys[c1 + l1] + ys[c2 + (LL - 1 - pos)] + ys[c3 + (LL - 1 - l1)];
    float sumD = dsv[d] + dsv[DINC + d] + dsv[2 * DINC + d] + dsv[3 * DINC + d];
    y = fmaf(xconv[((size_t)b * DINC + d) * LL + pos], sumD, y);
    yt[i] = y;
}

// ---------- 8. out_norm LN over 192 * silu(z) ----------
__global__ __launch_bounds__(256) void lnmul_k(const float* __restrict__ yt,
                                               const float* __restrict__ g,
                                               const float* __restrict__ bt,
                                               const float* __restrict__ zs,
                                               float* __restrict__ yact) {
    int pix = blockIdx.x * 4 + (threadIdx.x >> 6);
    int lane = threadIdx.x & 63;
    int b = pix / LL, pos = pix % LL;
    const float* yp = yt + (size_t)b * DINC * LL + pos;
    float v0 = yp[(size_t)lane * LL];
    float v1 = yp[(size_t)(lane + 64) * LL];
    float v2 = yp[(size_t)(lane + 128) * LL];
    float s = v0 + v1 + v2, q = v0 * v0 + v1 * v1 + v2 * v2;
    for (int o = 32; o; o >>= 1) { s += __shfl_xor(s, o, 64); q += __shfl_xor(q, o, 64); }
    float m = s * (1.f / 192.f);
    float inv = rsqrtf(q * (1.f / 192.f) - m * m + EPSF);
    float* op = yact + (size_t)pix * DINC;
    const float* zp = zs + (size_t)pix * DINC;
    op[lane] = ((v0 - m) * inv * g[lane] + bt[lane]) * zp[lane];
    op[lane + 64] = ((v1 - m) * inv * g[lane + 64] + bt[lane + 64]) * zp[lane + 64];
    op[lane + 128] = ((v2 - m) * inv * g[lane + 128] + bt[lane + 128]) * zp[lane + 128];
}

// ---------- 9. out_proj GEMM: LDS-tiled, M=64 N=96, K=192 in 2 chunks ----------
__global__ __launch_bounds__(256) void gemm2_k(const float* __restrict__ yact,
                                               const float* __restrict__ opw,
                                               const float* __restrict__ x,
                                               const float* __restrict__ sc1,
                                               float* __restrict__ vl) {
    __shared__ float xT[64 * PADK];
    __shared__ float wT[96 * PADK];
    int row0 = blockIdx.x * 64;
    int tc = threadIdx.x & 15;
    int tr = threadIdx.x >> 4;
    float acc[4][6] = {};
    for (int kc = 0; kc < 2; ++kc) {
        __syncthreads();
        for (int i = threadIdx.x; i < 1536; i += 256) {
            int f = i * 4, r = f / 96, k = f % 96;
            *(float4*)&xT[r * PADK + k] =
                *(const float4*)&yact[(size_t)(row0 + r) * DINC + kc * 96 + k];
        }
        for (int i = threadIdx.x; i < 2304; i += 256) {
            int f = i * 4, r = f / 96, k = f % 96;
            *(float4*)&wT[r * PADK + k] =
                *(const float4*)&opw[(size_t)r * DINC + kc * 96 + k];
        }
        __syncthreads();
        for (int k = 0; k < 96; ++k) {
            float xv[4], wv[6];
#pragma unroll
            for (int i = 0; i < 4; ++i) xv[i] = xT[(tr * 4 + i) * PADK + k];
#pragma unroll
            for (int j = 0; j < 6; ++j) wv[j] = wT[(tc + 16 * j) * PADK + k];
#pragma unroll
            for (int i = 0; i < 4; ++i)
#pragma unroll
                for (int j = 0; j < 6; ++j) acc[i][j] = fmaf(xv[i], wv[j], acc[i][j]);
        }
    }
    int row = row0 + tr * 4;
    int b = row / LL, pos = row % LL;
#pragma unroll
    for (int i = 0; i < 4; ++i)
#pragma unroll
        for (int j = 0; j < 6; ++j) {
            int col = tc + 16 * j;
            float v = fmaf(sc1[col], x[((size_t)b * DIMC + col) * LL + pos + i], acc[i][j]);
            vl[(size_t)(row + i) * DIMC + col] = v;
        }
}

// ---------- 10. LN2 + conv1x1(96->24) + BN + ReLU ----------
__global__ __launch_bounds__(256) void ln2conv1_k(const float* __restrict__ vl,
                                                  const float* __restrict__ g,
                                                  const float* __restrict__ bt,
                                                  const float* __restrict__ w1,
                                                  const float* __restrict__ g1,
                                                  const float* __restrict__ b1,
                                                  const float* __restrict__ m1,
                                                  const float* __restrict__ v1,
                                                  float* __restrict__ h1) {
    __shared__ float row[4][96];
    int wv = threadIdx.x >> 6, lane = threadIdx.x & 63;
    int pix = blockIdx.x * 4 + wv;
    const float* vr = vl + (size_t)pix * DIMC;
    float a0 = vr[lane];
    float a1 = (lane < 32) ? vr[64 + lane] : 0.f;
    float s = a0 + a1, q = a0 * a0 + a1 * a1;
    for (int o = 32; o; o >>= 1) { s += __shfl_xor(s, o, 64); q += __shfl_xor(q, o, 64); }
    float m = s * (1.f / 96.f);
    float inv = rsqrtf(q * (1.f / 96.f) - m * m + EPSF);
    row[wv][lane] = (a0 - m) * inv * g[lane] + bt[lane];
    if (lane < 32) row[wv][64 + lane] = (a1 - m) * inv * g[64 + lane] + bt[64 + lane];
    __syncthreads();
    if (lane < 24) {
        const float* wr = w1 + lane * 96;
        float acc = 0.f;
#pragma unroll 8
        for (int c = 0; c < 96; ++c) acc = fmaf(row[wv][c], wr[c], acc);
        float bn = (acc - m1[lane]) * rsqrtf(v1[lane] + EPSF) * g1[lane] + b1[lane];
        int b = pix / LL, pos = pix % LL;
        h1[((size_t)b * 24 + lane) * LL + pos] = fmaxf(bn, 0.f);
    }
}

// ---------- 11. conv3x3 (24->24) + BN + ReLU ----------
__global__ __launch_bounds__(256) void conv2_k(const float* __restrict__ h1,
                                               const float* __restrict__ w2,
                                               const float* __restrict__ g2,
                                               const float* __restrict__ b2,
                                               const float* __restrict__ m2,
                                               const float* __restrict__ v2,
                                               float* __restrict__ h2) {
    int i = blockIdx.x * 256 + threadIdx.x;
    int pos = i % LL, mo = (i / LL) % 24, b = i / (LL * 24);
    int hh = pos / WWD, ww = pos % WWD;
    float acc = 0.f;
    for (int c = 0; c < 24; ++c) {
        const float* src = h1 + ((size_t)b * 24 + c) * LL;
        const float* wk = w2 + ((size_t)(mo * 24 + c)) * 9;
#pragma unroll
        for (int ky = 0; ky < 3; ++ky) {
            int y = hh + ky - 1;
            if ((unsigned)y >= HH) continue;
#pragma unroll
            for (int kx = 0; kx < 3; ++kx) {
                int xq = ww + kx - 1;
                if ((unsigned)xq >= WWD) continue;
                acc = fmaf(wk[ky * 3 + kx], src[y * WWD + xq], acc);
            }
        }
    }
    float bn = (acc - m2[mo]) * rsqrtf(v2[mo] + EPSF) * g2[mo] + b2[mo];
    h2[i] = fmaxf(bn, 0.f);
}

// ---------- 12. conv1x1 (24->96) + BN ----------
__global__ __launch_bounds__(256) void conv3_k(const float* __restrict__ h2,
                                               const float* __restrict__ w3,
                                               const float* __restrict__ g3,
                                               const float* __restrict__ b3,
                                               const float* __restrict__ m3,
                                               const float* __restrict__ v3,
                                               float* __restrict__ h3) {
    int i = blockIdx.x * 256 + threadIdx.x;
    int pos = i % LL, c = (i / LL) % DIMC, b = i / (LL * DIMC);
    const float* wr = w3 + c * 24;
    float acc = 0.f;
#pragma unroll
    for (int mo = 0; mo < 24; ++mo)
        acc = fmaf(wr[mo], h2[((size_t)b * 24 + mo) * LL + pos], acc);
    h3[i] = (acc - m3[c]) * rsqrtf(v3[c] + EPSF) * g3[c] + b3[c];
}

// ---------- 13. SE pool ----------
__global__ __launch_bounds__(256) void pool_k(const float* __restrict__ h3,
                                              float* __restrict__ pooled) {
    int bc = blockIdx.x;
    const float* p = h3 + (size_t)bc * LL;
    float s = 0.f;
    for (int i = threadIdx.x; i < LL; i += 256) s += p[i];
    for (int o = 32; o; o >>= 1) s += __shfl_xor(s, o, 64);
    __shared__ float wsum[4];
    if ((threadIdx.x & 63) == 0) wsum[threadIdx.x >> 6] = s;
    __syncthreads();
    if (threadIdx.x == 0) pooled[bc] = (wsum[0] + wsum[1] + wsum[2] + wsum[3]) * (1.f / 3136.f);
}

// ---------- 14. SE MLP ----------
__global__ __launch_bounds__(128) void semlp_k(const float* __restrict__ pooled,
                                               const float* __restrict__ sw1,
                                               const float* __restrict__ sw2,
                                               float* __restrict__ sew) {
    __shared__ float pl[2][96];
    __shared__ float hid[2][24];
    for (int i = threadIdx.x; i < 192; i += 128) pl[i / 96][i % 96] = pooled[i];
    __syncthreads();
    if (threadIdx.x < 48) {
        int b = threadIdx.x / 24, mo = threadIdx.x % 24;
        float acc = 0.f;
        for (int c = 0; c < 96; ++c) acc = fmaf(pl[b][c], sw1[mo * 96 + c], acc);
        hid[b][mo] = fmaxf(acc, 0.f);
    }
    __syncthreads();
    for (int i = threadIdx.x; i < 192; i += 128) {
        int b = i / 96, c = i % 96;
        float acc = 0.f;
        for (int mo = 0; mo < 24; ++mo) acc = fmaf(hid[b][mo], sw2[c * 24 + mo], acc);
        sew[i] = 1.f / (1.f + __expf(-acc));
    }
}

// ---------- 15. final ----------
__global__ __launch_bounds__(256) void final_k(const float* __restrict__ h3,
                                               const float* __restrict__ sew,
                                               const float* __restrict__ vl,
                                               const float* __restrict__ sc2,
                                               float* __restrict__ out) {
    int i = blockIdx.x * 256 + threadIdx.x;
    int pos = i % LL, c = (i / LL) % DIMC, b = i / (LL * DIMC);
    out[i] = fmaf(h3[i], sew[b * DIMC + c],
                  sc2[c] * vl[((size_t)b * LL + pos) * DIMC + c]);
}

extern "C" void kernel_launch(void* const* d_in, const int* in_sizes, int n_in,
                              void* d_out, int out_size, void* d_ws, size_t ws_size,
                              hipStream_t stream) {
    const float* x    = (const float*)d_in[0];
    const float* n1g  = (const float*)d_in[1];
    const float* n1b  = (const float*)d_in[2];
    const float* ipw  = (const float*)d_in[3];
    const float* cw   = (const float*)d_in[4];
    const float* cb   = (const float*)d_in[5];
    const float* xpw  = (const float*)d_in[6];
    const float* dtw  = (const float*)d_in[7];
    const float* dtb  = (const float*)d_in[8];
    const float* alog = (const float*)d_in[9];
    const float* dsv  = (const float*)d_in[10];
    const float* ong  = (const float*)d_in[11];
    const float* onb  = (const float*)d_in[12];
    const float* opw  = (const float*)d_in[13];
    const float* sc1  = (const float*)d_in[14];
    const float* n2g  = (const float*)d_in[15];
    const float* n2b  = (const float*)d_in[16];
    const float* w1   = (const float*)d_in[17];
    const float* g1   = (const float*)d_in[18];
    const float* b1   = (const float*)d_in[19];
    const float* m1   = (const float*)d_in[20];
    const float* v1   = (const float*)d_in[21];
    const float* w2   = (const float*)d_in[22];
    const float* g2   = (const float*)d_in[23];
    const float* b2   = (const float*)d_in[24];
    const float* m2   = (const float*)d_in[25];
    const float* v2   = (const float*)d_in[26];
    const float* w3   = (const float*)d_in[27];
    const float* g3   = (const float*)d_in[28];
    const float* b3   = (const float*)d_in[29];
    const float* m3   = (const float*)d_in[30];
    const float* v3   = (const float*)d_in[31];
    const float* sw1  = (const float*)d_in[32];
    const float* sw2  = (const float*)d_in[33];
    const float* sc2  = (const float*)d_in[34];
    float* ws = (float*)d_ws;
    float* out = (float*)d_out;

    ln1_k<<<NPIX / 4, 256, 0, stream>>>(x, n1g, n1b, ws + OFF_XN);
    gemm1_k<<<dim3(NPIX / 64, 4), 256, 0, stream>>>(ws + OFF_XN, ipw, ws + OFF_XCRAW,
                                                    ws + OFF_ZS);
    dwconv_k<<<(BB * DINC * LL) / 256, 256, 0, stream>>>(ws + OFF_XCRAW, cw, cb, ws + OFF_XCONV);
    xdbl_k<<<(BB * KDIR * LL) / 4, 256, 0, stream>>>(ws + OFF_XCONV, xpw, ws + OFF_DTS, ws + OFF_BC);
    dpack_k<<<(BB * KDIR * DINC * LL) / 256, 256, 0, stream>>>(
        ws + OFF_DTS, ws + OFF_XCONV, dtw, dtb, (float2*)(ws + OFF_DPACK));

    scan1_k<<<(NCHAIN * NCH) / 16, 256, 0, stream>>>(
        (const float2*)(ws + OFF_DPACK), (const float2*)(ws + OFF_BC), alog,
        ws + OFF_HEND, ws + OFF_SUMD);
    scan2_k<<<NCHAIN / 16, 256, 0, stream>>>(ws + OFF_HEND, ws + OFF_SUMD, alog);
    scan3_k<<<(NCHAIN * NCH) / 16, 256, 0, stream>>>(
        (const float2*)(ws + OFF_DPACK), (const float2*)(ws + OFF_BC), alog,
        ws + OFF_HEND, ws + OFF_YS);

    combine_k<<<(BB * DINC * LL) / 256, 256, 0, stream>>>(ws + OFF_YS, ws + OFF_XCONV, dsv,
                                                          ws + OFF_YT);
    lnmul_k<<<NPIX / 4, 256, 0, stream>>>(ws + OFF_YT, ong, onb, ws + OFF_ZS, ws + OFF_YACT);
    gemm2_k<<<NPIX / 64, 256, 0, stream>>>(ws + OFF_YACT, opw, x, sc1, ws + OFF_VL);
    ln2conv1_k<<<NPIX / 4, 256, 0, stream>>>(ws + OFF_VL, n2g, n2b, w1, g1, b1, m1, v1,
                                             ws + OFF_H1);
    conv2_k<<<(BB * 24 * LL) / 256, 256, 0, stream>>>(ws + OFF_H1, w2, g2, b2, m2, v2,
                                                      ws + OFF_H2);
    conv3_k<<<(BB * DIMC * LL) / 256, 256, 0, stream>>>(ws + OFF_H2, w3, g3, b3, m3, v3,
                                                        ws + OFF_H3);
    pool_k<<<BB * DIMC, 256, 0, stream>>>(ws + OFF_H3, ws + OFF_POOL);
    semlp_k<<<1, 128, 0, stream>>>(ws + OFF_POOL, sw1, sw2, ws + OFF_SEW);
    final_k<<<(BB * DIMC * LL) / 256, 256, 0, stream>>>(ws + OFF_H3, ws + OFF_SEW, ws + OFF_VL,
                                                        sc2, out);
    (void)in_sizes; (void)n_in; (void)out_size; (void)ws_size;
}

// Round 4
// 349.630 us; speedup vs baseline: 5.1580x; 1.2756x over previous
//
#include <hip/hip_runtime.h>
#include <math.h>

#define DIMC 96
#define DINC 192
#define NSTC 16
#define DTRC 6
#define KDIR 4
#define BB   2
#define HH   56
#define WWD  56
#define LL   3136
#define NPIX (BB*LL)           // 6272
#define EPSF 1e-5f
#define NCH  49
#define LC   64
#define NCHAIN (BB*KDIR*DINC)  // 1536
#define NCOLS 152              // 4*38

// ---------- workspace layout (float offsets) ----------
#define OFF_XN     0u          // 602112  scratch: sumd during scan; H3 later
#define OFF_XCRAW  602112u     // 1204224 xc pre-conv NCHW; hend during scan; y_t after
#define OFF_ZS     1806336u    // 1204224 silu(z) (B,L,192)
#define OFF_XCONV  3010560u    // 1204224 silu(conv(xc)) NCHW
#define OFF_DTS    4214784u    // 150528  dts (B,K,L,6)
#define OFF_BC     4365312u    // 802816  (B,K,L,16,{B,C})
#define OFF_DPACK  5168128u    // 9633792 (B,K,192,L) float2 {delta, delta*x}
#define OFF_YS     14801920u   // 4816896 ys (B,K,192,L)
#define OFF_XCONVT OFF_YS      // 1204224 transposed xconv; dead before scan3 writes ys
#define OFF_HEND   OFF_XCRAW
#define OFF_SUMD   OFF_XN
#define OFF_YT     OFF_XCRAW
#define OFF_VL     OFF_DPACK
#define OFF_H1     (OFF_DPACK + 1000000u)
#define OFF_H2     (OFF_DPACK + 1200000u)
#define OFF_H3     OFF_XN
#define OFF_POOL   (OFF_DPACK + 1400000u)
#define OFF_SEW    (OFF_DPACK + 1400448u)

__device__ __forceinline__ float siluf(float x) { return x / (1.f + __expf(-x)); }
__device__ __forceinline__ float softplusf(float x) {
    return fmaxf(x, 0.f) + log1pf(__expf(-fabsf(x)));
}

// ---------- 1. fused LN1 + in_proj GEMM. grid (98,4) x 256 ----------
// Stages raw x (NCHW) transposed into LDS, per-pixel LN in LDS, then 64x96 GEMM band.
__global__ __launch_bounds__(256) void gemm1_k(const float* __restrict__ x,
                                               const float* __restrict__ g,
                                               const float* __restrict__ bt,
                                               const float* __restrict__ W,
                                               float* __restrict__ xcr,
                                               float* __restrict__ zs) {
    __shared__ float xT[64 * 97];
    __shared__ float wT[96 * 100];
    __shared__ float mA[64], iA[64];
    int row0 = blockIdx.x * 64;
    int b = row0 / LL, pos0 = row0 % LL;
    int c0 = blockIdx.y * 96;
    for (int f = threadIdx.x; f < 96 * 16; f += 256) {
        int ch = f >> 4, po = (f & 15) * 4;
        float4 v = *(const float4*)&x[((size_t)b * DIMC + ch) * LL + pos0 + po];
        xT[(po + 0) * 97 + ch] = v.x; xT[(po + 1) * 97 + ch] = v.y;
        xT[(po + 2) * 97 + ch] = v.z; xT[(po + 3) * 97 + ch] = v.w;
    }
    for (int f = threadIdx.x; f < 96 * 24; f += 256) {
        int r = f / 24, kq = (f % 24) * 4;
        *(float4*)&wT[r * 100 + kq] = *(const float4*)&W[(size_t)(c0 + r) * DIMC + kq];
    }
    __syncthreads();
    if (threadIdx.x < 64) {
        float s = 0.f, q = 0.f;
        const float* xr = &xT[threadIdx.x * 97];
        for (int c = 0; c < 96; ++c) { float v = xr[c]; s += v; q = fmaf(v, v, q); }
        float m = s * (1.f / 96.f);
        mA[threadIdx.x] = m;
        iA[threadIdx.x] = rsqrtf(q * (1.f / 96.f) - m * m + EPSF);
    }
    __syncthreads();
    for (int e = threadIdx.x; e < 64 * 96; e += 256) {
        int row = e / 96, col = e - row * 96;
        float v = xT[row * 97 + col];
        xT[row * 97 + col] = (v - mA[row]) * iA[row] * g[col] + bt[col];
    }
    __syncthreads();
    int tc = threadIdx.x & 15, tr = threadIdx.x >> 4;
    float acc[4][6] = {};
    for (int k = 0; k < 96; ++k) {
        float xv[4], wv[6];
#pragma unroll
        for (int i = 0; i < 4; ++i) xv[i] = xT[(4 * tr + i) * 97 + k];
#pragma unroll
        for (int j = 0; j < 6; ++j) wv[j] = wT[(tc + 16 * j) * 100 + k];
#pragma unroll
        for (int i = 0; i < 4; ++i)
#pragma unroll
            for (int j = 0; j < 6; ++j) acc[i][j] = fmaf(xv[i], wv[j], acc[i][j]);
    }
    int pos = pos0 + 4 * tr;
    if (c0 < DINC) {
#pragma unroll
        for (int j = 0; j < 6; ++j) {
            int col = c0 + tc + 16 * j;
            float4 v = make_float4(acc[0][j], acc[1][j], acc[2][j], acc[3][j]);
            *(float4*)&xcr[((size_t)b * DINC + col) * LL + pos] = v;
        }
    } else {
#pragma unroll
        for (int i = 0; i < 4; ++i)
#pragma unroll
            for (int j = 0; j < 6; ++j) {
                int zc = c0 - DINC + tc + 16 * j;
                zs[(size_t)(row0 + 4 * tr + i) * DINC + zc] = siluf(acc[i][j]);
            }
    }
}

// ---------- 2. depthwise 3x3 conv + silu, plane-in-LDS, emits xconv AND xconvT ----------
__global__ __launch_bounds__(448) void dwconvt_k(const float* __restrict__ xcr,
                                                 const float* __restrict__ cw,
                                                 const float* __restrict__ cb,
                                                 float* __restrict__ xconv,
                                                 float* __restrict__ xconvT) {
    __shared__ float P[56 * 57];
    __shared__ float T[56 * 57];
    int bd = blockIdx.x;  // b*192+d
    int d = bd % DINC;
    size_t base = (size_t)bd * LL;
    for (int t = threadIdx.x; t < LL; t += 448)
        P[(t / 56) * 57 + (t % 56)] = xcr[base + t];
    float wk[9];
#pragma unroll
    for (int q = 0; q < 9; ++q) wk[q] = cw[d * 9 + q];
    float bias = cb[d];
    __syncthreads();
    for (int t = threadIdx.x; t < LL; t += 448) {
        int h = t / 56, w = t % 56;
        float acc = bias;
#pragma unroll
        for (int ky = 0; ky < 3; ++ky) {
            int y = h + ky - 1;
            if ((unsigned)y >= 56u) continue;
#pragma unroll
            for (int kx = 0; kx < 3; ++kx) {
                int xq = w + kx - 1;
                if ((unsigned)xq >= 56u) continue;
                acc = fmaf(wk[ky * 3 + kx], P[y * 57 + xq], acc);
            }
        }
        float v = siluf(acc);
        xconv[base + t] = v;
        T[w * 57 + h] = v;
    }
    __syncthreads();
    for (int t = threadIdx.x; t < LL; t += 448)
        xconvT[base + t] = T[(t / 56) * 57 + (t % 56)];
}

// ---------- 3. x_proj as LDS-tiled GEMM: M=64, N=152, K=192 (4x48). grid 98 x 256 ----------
__global__ __launch_bounds__(256) void gemmx_k(const float* __restrict__ xconv,
                                               const float* __restrict__ xpw,
                                               float* __restrict__ dts,
                                               float* __restrict__ bc) {
    __shared__ float xT[64 * 49];
    __shared__ float wT[NCOLS * 52];
    int row0 = blockIdx.x * 64;
    int b = row0 / LL, pos0 = row0 % LL;
    int tc = threadIdx.x & 15, tr = threadIdx.x >> 4;
    float acc[4][10] = {};
    for (int kc = 0; kc < 4; ++kc) {
        if (kc) __syncthreads();
        for (int f = threadIdx.x; f < 48 * 16; f += 256) {
            int dd = f >> 4, po = (f & 15) * 4;
            float4 v = *(const float4*)&xconv[((size_t)b * DINC + kc * 48 + dd) * LL + pos0 + po];
            xT[(po + 0) * 49 + dd] = v.x; xT[(po + 1) * 49 + dd] = v.y;
            xT[(po + 2) * 49 + dd] = v.z; xT[(po + 3) * 49 + dd] = v.w;
        }
        for (int f = threadIdx.x; f < NCOLS * 12; f += 256) {
            int r = f / 12, kq = (f % 12) * 4;
            *(float4*)&wT[r * 52 + kq] = *(const float4*)&xpw[(size_t)r * DINC + kc * 48 + kq];
        }
        __syncthreads();
        for (int k = 0; k < 48; ++k) {
            float xv[4], wv[10];
#pragma unroll
            for (int i = 0; i < 4; ++i) xv[i] = xT[(4 * tr + i) * 49 + k];
#pragma unroll
            for (int j = 0; j < 10; ++j) {
                int c = tc + 16 * j;
                wv[j] = (c < NCOLS) ? wT[c * 52 + k] : 0.f;
            }
#pragma unroll
            for (int i = 0; i < 4; ++i)
#pragma unroll
                for (int j = 0; j < 10; ++j) acc[i][j] = fmaf(xv[i], wv[j], acc[i][j]);
        }
    }
    // epilogue: scatter to l-ordered dts / bc
#pragma unroll
    for (int i = 0; i < 4; ++i) {
        int pos = pos0 + 4 * tr + i;
        int h = pos / 56, w = pos - 56 * h;
        int lt = w * 56 + h;
#pragma unroll
        for (int j = 0; j < 10; ++j) {
            int c = tc + 16 * j;
            if (c >= NCOLS) continue;
            int k = c / 38, idx = c - 38 * k;
            int l = (k == 0) ? pos : (k == 1) ? lt : (k == 2) ? (LL - 1 - pos) : (LL - 1 - lt);
            size_t rb = (size_t)(b * KDIR + k) * LL + l;
            float v = acc[i][j];
            if (idx < DTRC)    dts[rb * DTRC + idx] = v;
            else if (idx < 22) bc[(rb * NSTC + idx - 6) * 2] = v;
            else               bc[(rb * NSTC + idx - 22) * 2 + 1] = v;
        }
    }
}

// ---------- 4. delta pack, coalesced via xconv/xconvT. grid 1536 x 448 ----------
__global__ __launch_bounds__(448) void dpack_k(const float* __restrict__ dts,
                                               const float* __restrict__ xconv,
                                               const float* __restrict__ xconvT,
                                               const float* __restrict__ dtw,
                                               const float* __restrict__ dtb,
                                               float2* __restrict__ dpk) {
    int p = blockIdx.x;                 // (b*4+k)*192+d
    int d = p % DINC, k = (p / DINC) % KDIR, b = p / (DINC * KDIR);
    float wr[DTRC];
#pragma unroll
    for (int r = 0; r < DTRC; ++r) wr[r] = dtw[((size_t)k * DINC + d) * DTRC + r];
    float bias = dtb[k * DINC + d];
    const float* dr0 = dts + (size_t)(b * KDIR + k) * LL * DTRC;
    size_t bd = ((size_t)b * DINC + d) * LL;
    const float* xsrc = (k & 1) ? (xconvT + bd) : (xconv + bd);
    bool rev = (k >= 2);
    float2* dpo = dpk + (size_t)p * LL;
    for (int l = threadIdx.x; l < LL; l += 448) {
        const float* dr = dr0 + (size_t)l * DTRC;
        float acc = bias;
#pragma unroll
        for (int r = 0; r < DTRC; ++r) acc = fmaf(wr[r], dr[r], acc);
        float dv = softplusf(acc);
        float xv = xsrc[rev ? (LL - 1 - l) : l];
        dpo[l] = make_float2(dv, dv * xv);
    }
}

// ---------- 5a. scan phase 1 ----------
__global__ __launch_bounds__(256) void scan1_k(const float2* __restrict__ dpk,
                                               const float2* __restrict__ bc,
                                               const float* __restrict__ alog,
                                               float* __restrict__ hend,
                                               float* __restrict__ sumd) {
    int gid = blockIdx.x * 16 + (threadIdx.x >> 4);
    int lane = threadIdx.x & 15;
    int chain = gid / NCH, c = gid % NCH;
    float An = -__expf(alog[(size_t)(chain % (KDIR * DINC)) * NSTC + lane]);
    const float2* dpr = dpk + (size_t)chain * LL + c * LC;
    const float2* bcr = bc + ((size_t)(chain / DINC) * LL + c * LC) * NSTC + lane;
    float h = 0.f, sd = 0.f;
#pragma unroll 4
    for (int l = 0; l < LC; ++l) {
        float2 dpv = dpr[l];
        float2 bcv = bcr[(size_t)l * NSTC];
        sd += dpv.x;
        h = fmaf(__expf(dpv.x * An), h, dpv.y * bcv.x);
    }
    hend[(size_t)gid * NSTC + lane] = h;
    if (lane == 0) sumd[gid] = sd;
}

// ---------- 5b. scan phase 2 ----------
__global__ __launch_bounds__(256) void scan2_k(float* __restrict__ hend,
                                               const float* __restrict__ sumd,
                                               const float* __restrict__ alog) {
    int chain = blockIdx.x * 16 + (threadIdx.x >> 4);
    int lane = threadIdx.x & 15;
    float An = -__expf(alog[(size_t)(chain % (KDIR * DINC)) * NSTC + lane]);
    float* hp = hend + (size_t)chain * NCH * NSTC + lane;
    const float* sp = sumd + (size_t)chain * NCH;
    float h = 0.f;
    for (int c = 0; c < NCH; ++c) {
        float he = hp[(size_t)c * NSTC];
        float sd = sp[c];
        hp[(size_t)c * NSTC] = h;
        h = fmaf(__expf(An * sd), h, he);
    }
}

// ---------- 5c. scan phase 3 ----------
__global__ __launch_bounds__(256) void scan3_k(const float2* __restrict__ dpk,
                                               const float2* __restrict__ bc,
                                               const float* __restrict__ alog,
                                               const float* __restrict__ hpre,
                                               float* __restrict__ ys) {
    int gid = blockIdx.x * 16 + (threadIdx.x >> 4);
    int lane = threadIdx.x & 15;
    int chain = gid / NCH, c = gid % NCH;
    float An = -__expf(alog[(size_t)(chain % (KDIR * DINC)) * NSTC + lane]);
    const float2* dpr = dpk + (size_t)chain * LL + c * LC;
    const float2* bcr = bc + ((size_t)(chain / DINC) * LL + c * LC) * NSTC + lane;
    float* yr = ys + (size_t)chain * LL + c * LC;
    float h = hpre[(size_t)gid * NSTC + lane];
#pragma unroll 4
    for (int l = 0; l < LC; ++l) {
        float2 dpv = dpr[l];
        float2 bcv = bcr[(size_t)l * NSTC];
        h = fmaf(__expf(dpv.x * An), h, dpv.y * bcv.x);
        float p = h * bcv.y;
        p += __shfl_xor(p, 1, 16);
        p += __shfl_xor(p, 2, 16);
        p += __shfl_xor(p, 4, 16);
        p += __shfl_xor(p, 8, 16);
        if (lane == 0) yr[l] = p;
    }
}

// ---------- 6. combine 4 directions (+ D*x) with in-LDS transpose. grid 384 x 448 ----------
__global__ __launch_bounds__(448) void combine_k(const float* __restrict__ ys,
                                                 const float* __restrict__ xconv,
                                                 const float* __restrict__ dsv,
                                                 float* __restrict__ yt) {
    __shared__ float T[56 * 57];
    int bd = blockIdx.x;  // b*192+d
    int d = bd % DINC, b = bd / DINC;
    const float* y0 = ys + ((size_t)(b * KDIR + 0) * DINC + d % DINC) * LL;
    const float* y1 = ys + ((size_t)(b * KDIR + 1) * DINC + d) * LL;
    const float* y2 = ys + ((size_t)(b * KDIR + 2) * DINC + d) * LL;
    const float* y3 = ys + ((size_t)(b * KDIR + 3) * DINC + d) * LL;
    for (int l = threadIdx.x; l < LL; l += 448)
        T[(l % 56) * 57 + (l / 56)] = y1[l] + y3[LL - 1 - l];
    float sD = dsv[d] + dsv[DINC + d] + dsv[2 * DINC + d] + dsv[3 * DINC + d];
    size_t base = (size_t)bd * LL;
    __syncthreads();
    for (int pos = threadIdx.x; pos < LL; pos += 448) {
        float y = y0[pos] + y2[LL - 1 - pos] + T[(pos / 56) * 57 + (pos % 56)];
        yt[base + pos] = fmaf(xconv[base + pos], sD, y);
    }
}

// ---------- 7. fused out_norm*silu(z) + out_proj + residual. grid 98 x 256 ----------
__global__ __launch_bounds__(256) void gemm2_k(const float* __restrict__ yt,
                                               const float* __restrict__ g,
                                               const float* __restrict__ bt,
                                               const float* __restrict__ zs,
                                               const float* __restrict__ opw,
                                               const float* __restrict__ x,
                                               const float* __restrict__ sc1,
                                               float* __restrict__ vl) {
    __shared__ float xT[64 * 193];
    __shared__ float wT[96 * 52];
    __shared__ float mA[64], iA[64];
    int row0 = blockIdx.x * 64;
    int b = row0 / LL, pos0 = row0 % LL;
    for (int f = threadIdx.x; f < 192 * 16; f += 256) {
        int ch = f >> 4, po = (f & 15) * 4;
        float4 v = *(const float4*)&yt[((size_t)b * DINC + ch) * LL + pos0 + po];
        xT[(po + 0) * 193 + ch] = v.x; xT[(po + 1) * 193 + ch] = v.y;
        xT[(po + 2) * 193 + ch] = v.z; xT[(po + 3) * 193 + ch] = v.w;
    }
    __syncthreads();
    if (threadIdx.x < 64) {
        float s = 0.f, q = 0.f;
        const float* xr = &xT[threadIdx.x * 193];
        for (int c = 0; c < 192; ++c) { float v = xr[c]; s += v; q = fmaf(v, v, q); }
        float m = s * (1.f / 192.f);
        mA[threadIdx.x] = m;
        iA[threadIdx.x] = rsqrtf(q * (1.f / 192.f) - m * m + EPSF);
    }
    __syncthreads();
    for (int e = threadIdx.x; e < 64 * 192; e += 256) {
        int row = e / 192, col = e - row * 192;
        float v = xT[row * 193 + col];
        float z = zs[(size_t)row0 * DINC + e];
        xT[row * 193 + col] = ((v - mA[row]) * iA[row] * g[col] + bt[col]) * z;
    }
    int tc = threadIdx.x & 15, tr = threadIdx.x >> 4;
    float acc[4][6] = {};
    for (int kc = 0; kc < 4; ++kc) {
        __syncthreads();
        for (int f = threadIdx.x; f < 96 * 12; f += 256) {
            int r = f / 12, kq = (f % 12) * 4;
            *(float4*)&wT[r * 52 + kq] = *(const float4*)&opw[(size_t)r * DINC + kc * 48 + kq];
        }
        __syncthreads();
        for (int k = 0; k < 48; ++k) {
            float xv[4], wv[6];
#pragma unroll
            for (int i = 0; i < 4; ++i) xv[i] = xT[(4 * tr + i) * 193 + kc * 48 + k];
#pragma unroll
            for (int j = 0; j < 6; ++j) wv[j] = wT[(tc + 16 * j) * 52 + k];
#pragma unroll
            for (int i = 0; i < 4; ++i)
#pragma unroll
                for (int j = 0; j < 6; ++j) acc[i][j] = fmaf(xv[i], wv[j], acc[i][j]);
        }
    }
#pragma unroll
    for (int i = 0; i < 4; ++i) {
        int pos = pos0 + 4 * tr + i;
#pragma unroll
        for (int j = 0; j < 6; ++j) {
            int col = tc + 16 * j;
            float v = fmaf(sc1[col], x[((size_t)b * DIMC + col) * LL + pos], acc[i][j]);
            vl[(size_t)(row0 + 4 * tr + i) * DIMC + col] = v;
        }
    }
}

// ---------- 8. LN2 + conv1x1(96->24) + BN + ReLU ----------
__global__ __launch_bounds__(256) void ln2conv1_k(const float* __restrict__ vl,
                                                  const float* __restrict__ g,
                                                  const float* __restrict__ bt,
                                                  const float* __restrict__ w1,
                                                  const float* __restrict__ g1,
                                                  const float* __restrict__ b1,
                                                  const float* __restrict__ m1,
                                                  const float* __restrict__ v1,
                                                  float* __restrict__ h1) {
    __shared__ float row[4][96];
    int wv = threadIdx.x >> 6, lane = threadIdx.x & 63;
    int pix = blockIdx.x * 4 + wv;
    const float* vr = vl + (size_t)pix * DIMC;
    float a0 = vr[lane];
    float a1 = (lane < 32) ? vr[64 + lane] : 0.f;
    float s = a0 + a1, q = a0 * a0 + a1 * a1;
    for (int o = 32; o; o >>= 1) { s += __shfl_xor(s, o, 64); q += __shfl_xor(q, o, 64); }
    float m = s * (1.f / 96.f);
    float inv = rsqrtf(q * (1.f / 96.f) - m * m + EPSF);
    row[wv][lane] = (a0 - m) * inv * g[lane] + bt[lane];
    if (lane < 32) row[wv][64 + lane] = (a1 - m) * inv * g[64 + lane] + bt[64 + lane];
    __syncthreads();
    if (lane < 24) {
        const float* wr = w1 + lane * 96;
        float acc = 0.f;
#pragma unroll 8
        for (int c = 0; c < 96; ++c) acc = fmaf(row[wv][c], wr[c], acc);
        float bn = (acc - m1[lane]) * rsqrtf(v1[lane] + EPSF) * g1[lane] + b1[lane];
        int b = pix / LL, pos = pix % LL;
        h1[((size_t)b * 24 + lane) * LL + pos] = fmaxf(bn, 0.f);
    }
}

// ---------- 9. conv3x3 (24->24) + BN + ReLU ----------
__global__ __launch_bounds__(256) void conv2_k(const float* __restrict__ h1,
                                               const float* __restrict__ w2,
                                               const float* __restrict__ g2,
                                               const float* __restrict__ b2,
                                               const float* __restrict__ m2,
                                               const float* __restrict__ v2,
                                               float* __restrict__ h2) {
    int i = blockIdx.x * 256 + threadIdx.x;
    int pos = i % LL, mo = (i / LL) % 24, b = i / (LL * 24);
    int hh = pos / WWD, ww = pos % WWD;
    float acc = 0.f;
    for (int c = 0; c < 24; ++c) {
        const float* src = h1 + ((size_t)b * 24 + c) * LL;
        const float* wk = w2 + ((size_t)(mo * 24 + c)) * 9;
#pragma unroll
        for (int ky = 0; ky < 3; ++ky) {
            int y = hh + ky - 1;
            if ((unsigned)y >= HH) continue;
#pragma unroll
            for (int kx = 0; kx < 3; ++kx) {
                int xq = ww + kx - 1;
                if ((unsigned)xq >= WWD) continue;
                acc = fmaf(wk[ky * 3 + kx], src[y * WWD + xq], acc);
            }
        }
    }
    float bn = (acc - m2[mo]) * rsqrtf(v2[mo] + EPSF) * g2[mo] + b2[mo];
    h2[i] = fmaxf(bn, 0.f);
}

// ---------- 10. conv1x1 (24->96) + BN ----------
__global__ __launch_bounds__(256) void conv3_k(const float* __restrict__ h2,
                                               const float* __restrict__ w3,
                                               const float* __restrict__ g3,
                                               const float* __restrict__ b3,
                                               const float* __restrict__ m3,
                                               const float* __restrict__ v3,
                                               float* __restrict__ h3) {
    int i = blockIdx.x * 256 + threadIdx.x;
    int pos = i % LL, c = (i / LL) % DIMC, b = i / (LL * DIMC);
    const float* wr = w3 + c * 24;
    float acc = 0.f;
#pragma unroll
    for (int mo = 0; mo < 24; ++mo)
        acc = fmaf(wr[mo], h2[((size_t)b * 24 + mo) * LL + pos], acc);
    h3[i] = (acc - m3[c]) * rsqrtf(v3[c] + EPSF) * g3[c] + b3[c];
}

// ---------- 11. SE pool ----------
__global__ __launch_bounds__(256) void pool_k(const float* __restrict__ h3,
                                              float* __restrict__ pooled) {
    int bc = blockIdx.x;
    const float* p = h3 + (size_t)bc * LL;
    float s = 0.f;
    for (int i = threadIdx.x; i < LL; i += 256) s += p[i];
    for (int o = 32; o; o >>= 1) s += __shfl_xor(s, o, 64);
    __shared__ float wsum[4];
    if ((threadIdx.x & 63) == 0) wsum[threadIdx.x >> 6] = s;
    __syncthreads();
    if (threadIdx.x == 0) pooled[bc] = (wsum[0] + wsum[1] + wsum[2] + wsum[3]) * (1.f / 3136.f);
}

// ---------- 12. SE MLP ----------
__global__ __launch_bounds__(128) void semlp_k(const float* __restrict__ pooled,
                                               const float* __restrict__ sw1,
                                               const float* __restrict__ sw2,
                                               float* __restrict__ sew) {
    __shared__ float pl[2][96];
    __shared__ float hid[2][24];
    for (int i = threadIdx.x; i < 192; i += 128) pl[i / 96][i % 96] = pooled[i];
    __syncthreads();
    if (threadIdx.x < 48) {
        int b = threadIdx.x / 24, mo = threadIdx.x % 24;
        float acc = 0.f;
        for (int c = 0; c < 96; ++c) acc = fmaf(pl[b][c], sw1[mo * 96 + c], acc);
        hid[b][mo] = fmaxf(acc, 0.f);
    }
    __syncthreads();
    for (int i = threadIdx.x; i < 192; i += 128) {
        int b = i / 96, c = i % 96;
        float acc = 0.f;
        for (int mo = 0; mo < 24; ++mo) acc = fmaf(hid[b][mo], sw2[c * 24 + mo], acc);
        sew[i] = 1.f / (1.f + __expf(-acc));
    }
}

// ---------- 13. final ----------
__global__ __launch_bounds__(256) void final_k(const float* __restrict__ h3,
                                               const float* __restrict__ sew,
                                               const float* __restrict__ vl,
                                               const float* __restrict__ sc2,
                                               float* __restrict__ out) {
    int i = blockIdx.x * 256 + threadIdx.x;
    int pos = i % LL, c = (i / LL) % DIMC, b = i / (LL * DIMC);
    out[i] = fmaf(h3[i], sew[b * DIMC + c],
                  sc2[c] * vl[((size_t)b * LL + pos) * DIMC + c]);
}

extern "C" void kernel_launch(void* const* d_in, const int* in_sizes, int n_in,
                              void* d_out, int out_size, void* d_ws, size_t ws_size,
                              hipStream_t stream) {
    const float* x    = (const float*)d_in[0];
    const float* n1g  = (const float*)d_in[1];
    const float* n1b  = (const float*)d_in[2];
    const float* ipw  = (const float*)d_in[3];
    const float* cw   = (const float*)d_in[4];
    const float* cb   = (const float*)d_in[5];
    const float* xpw  = (const float*)d_in[6];
    const float* dtw  = (const float*)d_in[7];
    const float* dtb  = (const float*)d_in[8];
    const float* alog = (const float*)d_in[9];
    const float* dsv  = (const float*)d_in[10];
    const float* ong  = (const float*)d_in[11];
    const float* onb  = (const float*)d_in[12];
    const float* opw  = (const float*)d_in[13];
    const float* sc1  = (const float*)d_in[14];
    const float* n2g  = (const float*)d_in[15];
    const float* n2b  = (const float*)d_in[16];
    const float* w1   = (const float*)d_in[17];
    const float* g1   = (const float*)d_in[18];
    const float* b1   = (const float*)d_in[19];
    const float* m1   = (const float*)d_in[20];
    const float* v1   = (const float*)d_in[21];
    const float* w2   = (const float*)d_in[22];
    const float* g2   = (const float*)d_in[23];
    const float* b2   = (const float*)d_in[24];
    const float* m2   = (const float*)d_in[25];
    const float* v2   = (const float*)d_in[26];
    const float* w3   = (const float*)d_in[27];
    const float* g3   = (const float*)d_in[28];
    const float* b3   = (const float*)d_in[29];
    const float* m3   = (const float*)d_in[30];
    const float* v3   = (const float*)d_in[31];
    const float* sw1  = (const float*)d_in[32];
    const float* sw2  = (const float*)d_in[33];
    const float* sc2  = (const float*)d_in[34];
    float* ws = (float*)d_ws;
    float* out = (float*)d_out;

    gemm1_k<<<dim3(NPIX / 64, 4), 256, 0, stream>>>(x, n1g, n1b, ipw,
                                                    ws + OFF_XCRAW, ws + OFF_ZS);
    dwconvt_k<<<BB * DINC, 448, 0, stream>>>(ws + OFF_XCRAW, cw, cb,
                                             ws + OFF_XCONV, ws + OFF_XCONVT);
    gemmx_k<<<NPIX / 64, 256, 0, stream>>>(ws + OFF_XCONV, xpw, ws + OFF_DTS, ws + OFF_BC);
    dpack_k<<<NCHAIN, 448, 0, stream>>>(ws + OFF_DTS, ws + OFF_XCONV, ws + OFF_XCONVT,
                                        dtw, dtb, (float2*)(ws + OFF_DPACK));

    scan1_k<<<(NCHAIN * NCH) / 16, 256, 0, stream>>>(
        (const float2*)(ws + OFF_DPACK), (const float2*)(ws + OFF_BC), alog,
        ws + OFF_HEND, ws + OFF_SUMD);
    scan2_k<<<NCHAIN / 16, 256, 0, stream>>>(ws + OFF_HEND, ws + OFF_SUMD, alog);
    scan3_k<<<(NCHAIN * NCH) / 16, 256, 0, stream>>>(
        (const float2*)(ws + OFF_DPACK), (const float2*)(ws + OFF_BC), alog,
        ws + OFF_HEND, ws + OFF_YS);

    combine_k<<<BB * DINC, 448, 0, stream>>>(ws + OFF_YS, ws + OFF_XCONV, dsv, ws + OFF_YT);
    gemm2_k<<<NPIX / 64, 256, 0, stream>>>(ws + OFF_YT, ong, onb, ws + OFF_ZS, opw, x, sc1,
                                           ws + OFF_VL);
    ln2conv1_k<<<NPIX / 4, 256, 0, stream>>>(ws + OFF_VL, n2g, n2b, w1, g1, b1, m1, v1,
                                             ws + OFF_H1);
    conv2_k<<<(BB * 24 * LL) / 256, 256, 0, stream>>>(ws + OFF_H1, w2, g2, b2, m2, v2,
                                                      ws + OFF_H2);
    conv3_k<<<(BB * DIMC * LL) / 256, 256, 0, stream>>>(ws + OFF_H2, w3, g3, b3, m3, v3,
                                                        ws + OFF_H3);
    pool_k<<<BB * DIMC, 256, 0, stream>>>(ws + OFF_H3, ws + OFF_POOL);
    semlp_k<<<1, 128, 0, stream>>>(ws + OFF_POOL, sw1, sw2, ws + OFF_SEW);
    final_k<<<(BB * DIMC * LL) / 256, 256, 0, stream>>>(ws + OFF_H3, ws + OFF_SEW, ws + OFF_VL,
                                                        sc2, out);
    (void)in_sizes; (void)n_in; (void)out_size; (void)ws_size;
}